// Round 1
// baseline (6186.980 us; speedup 1.0000x reference)
//
#include <hip/hip_runtime.h>
#include <math.h>

// ---------------------------------------------------------------------------
// JTNN decoder forward on MI355X.  fp32 v1: correctness-first, LDS-staged
// thread-per-channel GEMVs with 4/8-row register blocking.
//
// Key structural facts exploited:
//  * hbuf rows are write-once (row e written at step e/N, never mutated), so
//    new_h_all == hbuf[:E] and cur_o / root_o sums can be recomputed from the
//    FINAL hbuf -> no per-step side outputs need storing.
//  * only hbuf row E (zero-pad slot) needs initialization; all other rows are
//    written before any read (setup guarantees idx < t*N or == E).
// Workspace layout (floats): [0..7] loss/acc accumulators, [16..] hbuf
// ((E+1) x H = 33.8 MB).
// ---------------------------------------------------------------------------

namespace {

constexpr int T_  = 32;
constexpr int N_  = 1024;
constexpr int H_  = 256;
constexpr int L_  = 128;
constexpr int V_  = 800;
constexpr int B_  = 256;
constexpr int NB_ = 15;
constexpr int E_  = T_ * N_;      // 32768
constexpr int HB_OFF = 16;        // float offset of hbuf inside ws

__device__ __forceinline__ float sig_(float x){ return 1.f / (1.f + __expf(-x)); }

__device__ __forceinline__ float dot4_(const float4 a, const float4 b){
  return a.x*b.x + a.y*b.y + a.z*b.z + a.w*b.w;
}
__device__ __forceinline__ float4 ld4_(const float* p){ return *(const float4*)p; }

// ---- block-wide reductions (256 threads = 4 waves) ------------------------
__device__ __forceinline__ float blockReduceSum256(float v, volatile float* lds4){
  #pragma unroll
  for (int off = 32; off > 0; off >>= 1) v += __shfl_down(v, off, 64);
  const int wid  = threadIdx.x >> 6;
  const int lane = threadIdx.x & 63;
  if (lane == 0) lds4[wid] = v;
  __syncthreads();
  const float r = lds4[0] + lds4[1] + lds4[2] + lds4[3];
  __syncthreads();
  return r;
}

__device__ __forceinline__ void blockReduceMaxArg256(float& v, int& idx,
                                                     volatile float* ldsv,
                                                     volatile int* ldsi){
  #pragma unroll
  for (int off = 32; off > 0; off >>= 1){
    const float ov = __shfl_down(v,   off, 64);
    const int   oi = __shfl_down(idx, off, 64);
    if (ov > v || (ov == v && oi < idx)){ v = ov; idx = oi; }
  }
  const int wid  = threadIdx.x >> 6;
  if ((threadIdx.x & 63) == 0){ ldsv[wid] = v; ldsi[wid] = idx; }
  __syncthreads();
  float bv = ldsv[0]; int bi = ldsi[0];
  #pragma unroll
  for (int w = 1; w < 4; ++w){
    const float ov = ldsv[w]; const int oi = ldsi[w];
    if (ov > bv || (ov == bv && oi < bi)){ bv = ov; bi = oi; }
  }
  __syncthreads();
  v = bv; idx = bi;
}

// ---- init: zero accumulators + hbuf zero-pad row --------------------------
__global__ __launch_bounds__(256) void k_init(float* __restrict__ ws){
  const int tid = threadIdx.x;
  if (tid < 8) ws[tid] = 0.f;
  ws[HB_OFF + (size_t)E_ * H_ + tid] = 0.f;   // row E = zero pad slot
}

// ---- one GRU scan step: rows [t*N, (t+1)*N) -------------------------------
// grid 256 blocks (4 rows each), 256 threads (one per output channel).
__global__ __launch_bounds__(256) void k_gru(
    const float* __restrict__ emb,
    const float* __restrict__ Wz, const float* __restrict__ Wzb,
    const float* __restrict__ Wr, const float* __restrict__ Wrb,
    const float* __restrict__ Ur,
    const float* __restrict__ Wh, const float* __restrict__ Whb,
    const int* __restrict__ word_ids, const int* __restrict__ h_nei,
    float* __restrict__ hbuf, int t)
{
  __shared__ __align__(16) float xs[4][H_];       // x rows
  __shared__ __align__(16) float sh[4][H_];       // sum_h rows
  __shared__ __align__(16) float hn[5][4][H_];    // staged neighbor group
  __shared__ __align__(16) float gl[4][H_];       // gated rows
  __shared__ int s_wid[4];
  __shared__ int s_hidx[4][NB_];

  const int tid  = threadIdx.x;
  const int base = t * N_ + blockIdx.x * 4;       // first global message row

  if (tid < 4) s_wid[tid] = word_ids[base + tid];
  if (tid < 4 * NB_){
    const int r = tid / NB_, nb = tid % NB_;
    s_hidx[r][nb] = h_nei[(base + r) * NB_ + nb];
  }
  __syncthreads();

  const int c = tid;                               // this thread's channel
  #pragma unroll
  for (int r = 0; r < 4; ++r){
    xs[r][c] = emb[s_wid[r] * H_ + c];
    sh[r][c] = 0.f;
  }
  __syncthreads();

  // xr = x @ Wr^T + b_r  (kept in registers, per channel)
  float xr[4];
  {
    const float b = Wrb[c];
    float a0 = b, a1 = b, a2 = b, a3 = b;
    const float* wrow = Wr + (size_t)c * H_;
    for (int k = 0; k < H_; k += 4){
      const float4 w = ld4_(wrow + k);
      a0 += dot4_(w, ld4_(&xs[0][k]));
      a1 += dot4_(w, ld4_(&xs[1][k]));
      a2 += dot4_(w, ld4_(&xs[2][k]));
      a3 += dot4_(w, ld4_(&xs[3][k]));
    }
    xr[0] = a0; xr[1] = a1; xr[2] = a2; xr[3] = a3;
  }

  // gated = sum_nb sigmoid(xr + Ur h_nei) * h_nei  (3 groups of 5 neighbors)
  float gated[4] = {0.f, 0.f, 0.f, 0.f};
  const float* urow = Ur + (size_t)c * H_;
  for (int g = 0; g < 3; ++g){
    #pragma unroll
    for (int q = 0; q < 5; ++q){
      #pragma unroll
      for (int r = 0; r < 4; ++r){
        const float v = hbuf[(size_t)s_hidx[r][g*5 + q] * H_ + c];
        hn[q][r][c] = v;
        sh[r][c] += v;                 // accumulate sum_h while staging
      }
    }
    __syncthreads();
    float acc[5][4];
    #pragma unroll
    for (int q = 0; q < 5; ++q){
      #pragma unroll
      for (int r = 0; r < 4; ++r) acc[q][r] = 0.f;
    }
    for (int k = 0; k < H_; k += 4){
      const float4 w = ld4_(urow + k);
      #pragma unroll
      for (int q = 0; q < 5; ++q){
        #pragma unroll
        for (int r = 0; r < 4; ++r){
          acc[q][r] += dot4_(w, ld4_(&hn[q][r][k]));
        }
      }
    }
    #pragma unroll
    for (int q = 0; q < 5; ++q){
      #pragma unroll
      for (int r = 0; r < 4; ++r){
        const float rg = sig_(xr[r] + acc[q][r]);
        gated[r] += rg * hn[q][r][c];
      }
    }
    __syncthreads();                   // hn reused next group
  }

  // z = sigmoid([x, sum_h] @ Wz^T + b_z)
  float zg[4];
  {
    const float b = Wzb[c];
    float a0 = b, a1 = b, a2 = b, a3 = b;
    const float* wrow = Wz + (size_t)c * (2 * H_);
    for (int k = 0; k < H_; k += 4){
      const float4 w = ld4_(wrow + k);
      a0 += dot4_(w, ld4_(&xs[0][k]));
      a1 += dot4_(w, ld4_(&xs[1][k]));
      a2 += dot4_(w, ld4_(&xs[2][k]));
      a3 += dot4_(w, ld4_(&xs[3][k]));
    }
    for (int k = 0; k < H_; k += 4){
      const float4 w = ld4_(wrow + H_ + k);
      a0 += dot4_(w, ld4_(&sh[0][k]));
      a1 += dot4_(w, ld4_(&sh[1][k]));
      a2 += dot4_(w, ld4_(&sh[2][k]));
      a3 += dot4_(w, ld4_(&sh[3][k]));
    }
    zg[0] = sig_(a0); zg[1] = sig_(a1); zg[2] = sig_(a2); zg[3] = sig_(a3);
  }

  // gated -> LDS (Wh needs it as a k-vector)
  #pragma unroll
  for (int r = 0; r < 4; ++r) gl[r][c] = gated[r];
  __syncthreads();

  // h_tilde = tanh([x, gated] @ Wh^T + b_h);  new_h -> hbuf
  {
    const float b = Whb[c];
    float a0 = b, a1 = b, a2 = b, a3 = b;
    const float* wrow = Wh + (size_t)c * (2 * H_);
    for (int k = 0; k < H_; k += 4){
      const float4 w = ld4_(wrow + k);
      a0 += dot4_(w, ld4_(&xs[0][k]));
      a1 += dot4_(w, ld4_(&xs[1][k]));
      a2 += dot4_(w, ld4_(&xs[2][k]));
      a3 += dot4_(w, ld4_(&xs[3][k]));
    }
    for (int k = 0; k < H_; k += 4){
      const float4 w = ld4_(wrow + H_ + k);
      a0 += dot4_(w, ld4_(&gl[0][k]));
      a1 += dot4_(w, ld4_(&gl[1][k]));
      a2 += dot4_(w, ld4_(&gl[2][k]));
      a3 += dot4_(w, ld4_(&gl[3][k]));
    }
    const float ht[4] = {tanhf(a0), tanhf(a1), tanhf(a2), tanhf(a3)};
    #pragma unroll
    for (int r = 0; r < 4; ++r){
      const float nh = (1.f - zg[r]) * sh[r][c] + zg[r] * ht[r];
      hbuf[(size_t)(base + r) * H_ + c] = nh;
    }
  }
}

// ---- word-prediction head: B roots + E edges ------------------------------
// grid 4128 blocks x 8 rows, 256 threads.
__global__ __launch_bounds__(256) void k_pred(
    const float* __restrict__ hbuf,
    const float* __restrict__ Ww, const float* __restrict__ Wb,
    const float* __restrict__ Wo, const float* __restrict__ Wob,
    const float* __restrict__ xtree,
    const int* __restrict__ contexts, const int* __restrict__ pred_targets,
    const int* __restrict__ direction, const int* __restrict__ root_word_ids,
    float* __restrict__ accum)
{
  __shared__ __align__(16) float iv[8][H_ + L_];
  __shared__ __align__(16) float hd[8][H_];
  __shared__ __align__(16) float sc[8][V_];
  __shared__ float rv[4];
  __shared__ int   ri[4];
  __shared__ int   s_ctx[8], s_tgt[8];
  __shared__ float s_mask[8];

  const int tid = threadIdx.x;
  const int p0  = blockIdx.x * 8;

  if (tid < 8){
    const int p = p0 + tid;
    if (p < B_){ s_ctx[tid] = p; s_tgt[tid] = root_word_ids[p]; s_mask[tid] = 1.f; }
    else {
      const int e = p - B_;
      s_ctx[tid] = contexts[e]; s_tgt[tid] = pred_targets[e];
      s_mask[tid] = (float)direction[e];
    }
  }
  __syncthreads();

  // stage iv = [hid(256) | xtree[ctx](128)]
  {
    const int c = tid;
    #pragma unroll
    for (int r = 0; r < 8; ++r){
      const int p = p0 + r;
      iv[r][c] = (p < B_) ? 0.f : hbuf[(size_t)(p - B_) * H_ + c];
    }
    if (c < L_){
      #pragma unroll
      for (int r = 0; r < 8; ++r) iv[r][H_ + c] = xtree[(size_t)s_ctx[r] * L_ + c];
    }
  }
  __syncthreads();

  // hidden = relu(iv @ Ww^T + Wb)
  {
    const int c = tid;
    const float b = Wb[c];
    float acc[8];
    #pragma unroll
    for (int r = 0; r < 8; ++r) acc[r] = b;
    const float* wrow = Ww + (size_t)c * (H_ + L_);
    for (int k = 0; k < H_ + L_; k += 4){
      const float4 w = ld4_(wrow + k);
      #pragma unroll
      for (int r = 0; r < 8; ++r) acc[r] += dot4_(w, ld4_(&iv[r][k]));
    }
    #pragma unroll
    for (int r = 0; r < 8; ++r) hd[r][c] = fmaxf(acc[r], 0.f);
  }
  __syncthreads();

  // scores = hidden @ Wo^T + Wob   (thread covers channels tid+256*i)
  const int  c0 = tid, c1 = tid + 256, c2 = tid + 512;
  const bool v3 = (tid < V_ - 768);              // 32 threads own a 4th channel
  const int  c3 = v3 ? (tid + 768) : (V_ - 1);   // clamped: loads stay in-bounds
  float a0[8], a1[8], a2[8], a3[8];
  {
    const float b0 = Wob[c0], b1 = Wob[c1], b2 = Wob[c2], b3 = Wob[c3];
    #pragma unroll
    for (int r = 0; r < 8; ++r){ a0[r] = b0; a1[r] = b1; a2[r] = b2; a3[r] = b3; }
    const float* w0 = Wo + (size_t)c0 * H_;
    const float* w1 = Wo + (size_t)c1 * H_;
    const float* w2 = Wo + (size_t)c2 * H_;
    const float* w3 = Wo + (size_t)c3 * H_;
    for (int k = 0; k < H_; k += 4){
      const float4 q0 = ld4_(w0 + k), q1 = ld4_(w1 + k);
      const float4 q2 = ld4_(w2 + k), q3 = ld4_(w3 + k);
      #pragma unroll
      for (int r = 0; r < 8; ++r){
        const float4 h = ld4_(&hd[r][k]);
        a0[r] += dot4_(q0, h); a1[r] += dot4_(q1, h);
        a2[r] += dot4_(q2, h); a3[r] += dot4_(q3, h);
      }
    }
  }
  #pragma unroll
  for (int r = 0; r < 8; ++r){
    sc[r][c0] = a0[r]; sc[r][c1] = a1[r]; sc[r][c2] = a2[r];
    if (v3) sc[r][c3] = a3[r];
  }
  __syncthreads();

  // per-row log-softmax NLL + argmax accuracy
  for (int r = 0; r < 8; ++r){
    float lmax = a0[r]; int larg = c0;
    if (a1[r] > lmax){ lmax = a1[r]; larg = c1; }
    if (a2[r] > lmax){ lmax = a2[r]; larg = c2; }
    if (v3 && a3[r] > lmax){ lmax = a3[r]; larg = c3; }
    blockReduceMaxArg256(lmax, larg, rv, ri);
    float ls = __expf(a0[r] - lmax) + __expf(a1[r] - lmax) + __expf(a2[r] - lmax);
    if (v3) ls += __expf(a3[r] - lmax);
    const float gs = blockReduceSum256(ls, rv);
    if (tid == 0){
      const int   tgt  = s_tgt[r];
      const float logZ = lmax + __logf(gs);
      const float nll  = logZ - sc[r][tgt];
      const float m    = s_mask[r];
      atomicAdd(&accum[0], nll * m);
      atomicAdd(&accum[1], (larg == tgt) ? m : 0.f);
      atomicAdd(&accum[2], m);
    }
  }
}

// ---- stop head: E edges + B roots -----------------------------------------
__global__ __launch_bounds__(256) void k_stop(
    const float* __restrict__ hbuf, const float* __restrict__ emb,
    const float* __restrict__ Ui, const float* __restrict__ Uib,
    const float* __restrict__ Uw, const float* __restrict__ Ub,
    const float* __restrict__ Uo, const float* __restrict__ Uob,
    const float* __restrict__ xtree,
    const int* __restrict__ word_ids, const int* __restrict__ o_nei,
    const int* __restrict__ contexts, const int* __restrict__ direction,
    const int* __restrict__ root_word_ids, const int* __restrict__ root_o_idx,
    float* __restrict__ accum)
{
  __shared__ __align__(16) float inp[8][2 * H_];
  __shared__ __align__(16) float iv[8][H_ + L_];
  __shared__ float rv[4];
  __shared__ int   s_wid[8], s_ctx[8];
  __shared__ float s_tgt[8];
  __shared__ int   s_oidx[8][NB_];

  const int tid = threadIdx.x;
  const int p0  = blockIdx.x * 8;

  if (tid < 8){
    const int s = p0 + tid;
    if (s < E_){
      s_wid[tid] = word_ids[s]; s_ctx[tid] = contexts[s];
      s_tgt[tid] = (float)direction[s];
    } else {
      const int b = s - E_;
      s_wid[tid] = root_word_ids[b]; s_ctx[tid] = b; s_tgt[tid] = 0.f;
    }
  }
  if (tid < 8 * NB_){
    const int r = tid / NB_, nb = tid % NB_;
    const int s = p0 + r;
    s_oidx[r][nb] = (s < E_) ? o_nei[(size_t)s * NB_ + nb]
                             : root_o_idx[(size_t)(s - E_) * NB_ + nb];
  }
  __syncthreads();

  // stage [x | sum_o] (sum over final hbuf: rows are write-once, so this
  // equals the reference's per-step cur_o)
  {
    const int c = tid;
    #pragma unroll
    for (int r = 0; r < 8; ++r){
      inp[r][c] = emb[(size_t)s_wid[r] * H_ + c];
      float o = 0.f;
      #pragma unroll
      for (int nb = 0; nb < NB_; ++nb)
        o += hbuf[(size_t)s_oidx[r][nb] * H_ + c];
      inp[r][H_ + c] = o;
    }
  }
  __syncthreads();

  // h1 = relu(inp @ Ui^T + Uib) -> iv[:, :256]; stage xtree -> iv[:, 256:]
  {
    const int c = tid;
    const float b = Uib[c];
    float acc[8];
    #pragma unroll
    for (int r = 0; r < 8; ++r) acc[r] = b;
    const float* wrow = Ui + (size_t)c * (2 * H_);
    for (int k = 0; k < 2 * H_; k += 4){
      const float4 w = ld4_(wrow + k);
      #pragma unroll
      for (int r = 0; r < 8; ++r) acc[r] += dot4_(w, ld4_(&inp[r][k]));
    }
    #pragma unroll
    for (int r = 0; r < 8; ++r) iv[r][c] = fmaxf(acc[r], 0.f);
    if (c < L_){
      #pragma unroll
      for (int r = 0; r < 8; ++r) iv[r][H_ + c] = xtree[(size_t)s_ctx[r] * L_ + c];
    }
  }
  __syncthreads();

  // h2 = relu(iv @ Uw^T + Ub); s = h2 . Uo + Uob
  float p[8];
  {
    const int c = tid;
    const float b = Ub[c];
    float acc[8];
    #pragma unroll
    for (int r = 0; r < 8; ++r) acc[r] = b;
    const float* wrow = Uw + (size_t)c * (H_ + L_);
    for (int k = 0; k < H_ + L_; k += 4){
      const float4 w = ld4_(wrow + k);
      #pragma unroll
      for (int r = 0; r < 8; ++r) acc[r] += dot4_(w, ld4_(&iv[r][k]));
    }
    const float uo = Uo[c];
    #pragma unroll
    for (int r = 0; r < 8; ++r) p[r] = uo * fmaxf(acc[r], 0.f);
  }
  for (int r = 0; r < 8; ++r){
    float sv = blockReduceSum256(p[r], rv);
    if (tid == 0){
      sv += Uob[0];
      const float tgt = s_tgt[r];
      const float bce = fmaxf(sv, 0.f) - sv * tgt + log1pf(__expf(-fabsf(sv)));
      atomicAdd(&accum[3], bce);
      const float pb = (sv >= 0.f) ? 1.f : 0.f;
      atomicAdd(&accum[4], (pb == tgt) ? 1.f : 0.f);
    }
  }
}

// ---- finalize --------------------------------------------------------------
__global__ void k_final(const float* __restrict__ ws, float* __restrict__ out){
  if (threadIdx.x == 0 && blockIdx.x == 0){
    out[0] = ws[0] / (float)B_;               // pred_loss
    out[1] = ws[3] / (float)B_;               // stop_loss
    out[2] = ws[1] / ws[2];                   // pred_acc
    out[3] = ws[4] / (float)(E_ + B_);        // stop_acc
  }
}

} // anonymous namespace

extern "C" void kernel_launch(void* const* d_in, const int* in_sizes, int n_in,
                              void* d_out, int out_size, void* d_ws, size_t ws_size,
                              hipStream_t stream)
{
  const float* emb   = (const float*)d_in[0];
  const float* Wz    = (const float*)d_in[1];
  const float* Wzb   = (const float*)d_in[2];
  const float* Wr    = (const float*)d_in[3];
  const float* Wrb   = (const float*)d_in[4];
  const float* Ur    = (const float*)d_in[5];
  const float* Wh    = (const float*)d_in[6];
  const float* Whb   = (const float*)d_in[7];
  const float* Ww    = (const float*)d_in[8];
  const float* Wb    = (const float*)d_in[9];
  const float* Wo    = (const float*)d_in[10];
  const float* Wob   = (const float*)d_in[11];
  const float* Uw    = (const float*)d_in[12];
  const float* Ub    = (const float*)d_in[13];
  const float* Ui    = (const float*)d_in[14];
  const float* Uib   = (const float*)d_in[15];
  const float* Uo    = (const float*)d_in[16];
  const float* Uob   = (const float*)d_in[17];
  const float* xtree = (const float*)d_in[18];
  const int* word_ids     = (const int*)d_in[19];
  const int* h_nei_idx    = (const int*)d_in[20];
  const int* o_nei_idx    = (const int*)d_in[21];
  const int* contexts     = (const int*)d_in[22];
  const int* pred_targets = (const int*)d_in[23];
  const int* direction    = (const int*)d_in[24];
  const int* root_word_ids = (const int*)d_in[25];
  const int* root_o_idx    = (const int*)d_in[26];

  float* ws   = (float*)d_ws;
  float* hbuf = ws + HB_OFF;
  float* out  = (float*)d_out;

  hipLaunchKernelGGL(k_init, dim3(1), dim3(256), 0, stream, ws);

  for (int t = 0; t < T_; ++t){
    hipLaunchKernelGGL(k_gru, dim3(N_ / 4), dim3(256), 0, stream,
                       emb, Wz, Wzb, Wr, Wrb, Ur, Wh, Whb,
                       word_ids, h_nei_idx, hbuf, t);
  }

  hipLaunchKernelGGL(k_pred, dim3((B_ + E_) / 8), dim3(256), 0, stream,
                     hbuf, Ww, Wb, Wo, Wob, xtree,
                     contexts, pred_targets, direction, root_word_ids, ws);

  hipLaunchKernelGGL(k_stop, dim3((E_ + B_) / 8), dim3(256), 0, stream,
                     hbuf, emb, Ui, Uib, Uw, Ub, Uo, Uob, xtree,
                     word_ids, o_nei_idx, contexts, direction,
                     root_word_ids, root_o_idx, ws);

  hipLaunchKernelGGL(k_final, dim3(1), dim3(1), 0, stream, ws, out);
}

// Round 2
// 3798.357 us; speedup vs baseline: 1.6289x; 1.6289x over previous
//
#include <hip/hip_runtime.h>
#include <math.h>

// ---------------------------------------------------------------------------
// JTNN decoder forward on MI355X.  v2: bf16 MFMA heads (16x16x32), bf16 hbuf.
//  * hbuf rows are write-once -> heads recompute everything from final hbuf.
//  * k_pred / k_stop: per-wave 16-row tiles; A-frags gathered directly from
//    global bf16 (hbuf/emb/xtree) or LDS (hidden roundtrip); B-frags read
//    straight from bf16 weight copies (L2-resident). Online softmax for the
//    800-wide vocab GEMM -> no score matrix materialized.
//  * MFMA layouts (learn_hip-verified): A[m=lane&15][k=8*(lane>>4)+j],
//    B[k=8*(lane>>4)+j][n=lane&15], D[row=4*(lane>>4)+i][col=lane&15].
// ws layout: [0,256)B accum | hbuf bf16 (E+1)x256 | bf16 copies of
// emb/xtree/Ww/Wo/Ui/Uw  (~18.3 MB total).
// ---------------------------------------------------------------------------

namespace {

constexpr int T_  = 32;
constexpr int N_  = 1024;
constexpr int H_  = 256;
constexpr int NB_ = 15;
constexpr int E_  = T_ * N_;      // 32768
constexpr int B_  = 256;

typedef unsigned short u16;
typedef unsigned int  uix4  __attribute__((ext_vector_type(4)));
typedef __bf16        bf16x8 __attribute__((ext_vector_type(8)));
typedef float         f32x4  __attribute__((ext_vector_type(4)));

__device__ __forceinline__ float sig_(float x){ return 1.f / (1.f + __expf(-x)); }
__device__ __forceinline__ float dot4_(const float4 a, const float4 b){
  return a.x*b.x + a.y*b.y + a.z*b.z + a.w*b.w;
}
__device__ __forceinline__ float4 ld4_(const float* p){ return *(const float4*)p; }

__device__ __forceinline__ float b2f(u16 u){
  union { unsigned int i; float f; } v; v.i = ((unsigned int)u) << 16; return v.f;
}
__device__ __forceinline__ u16 f2b(float f){
  union { float f; unsigned int i; } v; v.f = f;
  const unsigned int r = v.i + 0x7fffu + ((v.i >> 16) & 1u);
  return (u16)(r >> 16);
}
__device__ __forceinline__ f32x4 mfma16(uix4 a, uix4 b, f32x4 c){
  return __builtin_amdgcn_mfma_f32_16x16x32_bf16(
      __builtin_bit_cast(bf16x8, a), __builtin_bit_cast(bf16x8, b), c, 0, 0, 0);
}

// ---- fp32 -> bf16 weight/embedding conversion (once per launch) -----------
__global__ __launch_bounds__(256) void k_cvt(
    const float* __restrict__ emb, const float* __restrict__ xt,
    const float* __restrict__ Ww,  const float* __restrict__ Wo,
    const float* __restrict__ Ui,  const float* __restrict__ Uw,
    u16* __restrict__ o_emb, u16* __restrict__ o_xt, u16* __restrict__ o_Ww,
    u16* __restrict__ o_Wo,  u16* __restrict__ o_Ui, u16* __restrict__ o_Uw)
{
  int i = blockIdx.x * 256 + threadIdx.x;
  if (i < 204800){ o_emb[i] = f2b(emb[i]); return; }  i -= 204800;
  if (i <  32768){ o_xt[i]  = f2b(xt[i]);  return; }  i -=  32768;
  if (i <  98304){ o_Ww[i]  = f2b(Ww[i]);  return; }  i -=  98304;
  if (i < 204800){ o_Wo[i]  = f2b(Wo[i]);  return; }  i -= 204800;
  if (i < 131072){ o_Ui[i]  = f2b(Ui[i]);  return; }  i -= 131072;
  if (i <  98304){ o_Uw[i]  = f2b(Uw[i]); }
}

// ---- init: zero accumulators + hbuf zero-pad row --------------------------
__global__ __launch_bounds__(256) void k_init(float* __restrict__ acc,
                                              u16* __restrict__ hb16){
  const int tid = threadIdx.x;
  if (tid < 16) acc[tid] = 0.f;
  hb16[(size_t)E_ * H_ + tid] = 0;   // row E = zero pad slot
}

// ---- one GRU scan step (fp32 compute, bf16 state) -------------------------
__global__ __launch_bounds__(256) void k_gru(
    const float* __restrict__ emb,
    const float* __restrict__ Wz, const float* __restrict__ Wzb,
    const float* __restrict__ Wr, const float* __restrict__ Wrb,
    const float* __restrict__ Ur,
    const float* __restrict__ Wh, const float* __restrict__ Whb,
    const int* __restrict__ word_ids, const int* __restrict__ h_nei,
    u16* __restrict__ hb16, int t)
{
  __shared__ __align__(16) float xs[4][H_];
  __shared__ __align__(16) float sh[4][H_];
  __shared__ __align__(16) float hn[5][4][H_];
  __shared__ __align__(16) float gl[4][H_];
  __shared__ int s_wid[4];
  __shared__ int s_hidx[4][NB_];

  const int tid  = threadIdx.x;
  const int base = t * N_ + blockIdx.x * 4;

  if (tid < 4) s_wid[tid] = word_ids[base + tid];
  if (tid < 4 * NB_){
    const int r = tid / NB_, nb = tid % NB_;
    s_hidx[r][nb] = h_nei[(base + r) * NB_ + nb];
  }
  __syncthreads();

  const int c = tid;
  #pragma unroll
  for (int r = 0; r < 4; ++r){
    xs[r][c] = emb[s_wid[r] * H_ + c];
    sh[r][c] = 0.f;
  }
  __syncthreads();

  float xr[4];
  {
    const float b = Wrb[c];
    float a0 = b, a1 = b, a2 = b, a3 = b;
    const float* wrow = Wr + (size_t)c * H_;
    for (int k = 0; k < H_; k += 4){
      const float4 w = ld4_(wrow + k);
      a0 += dot4_(w, ld4_(&xs[0][k]));
      a1 += dot4_(w, ld4_(&xs[1][k]));
      a2 += dot4_(w, ld4_(&xs[2][k]));
      a3 += dot4_(w, ld4_(&xs[3][k]));
    }
    xr[0] = a0; xr[1] = a1; xr[2] = a2; xr[3] = a3;
  }

  float gated[4] = {0.f, 0.f, 0.f, 0.f};
  const float* urow = Ur + (size_t)c * H_;
  for (int g = 0; g < 3; ++g){
    #pragma unroll
    for (int q = 0; q < 5; ++q){
      #pragma unroll
      for (int r = 0; r < 4; ++r){
        const float v = b2f(hb16[(size_t)s_hidx[r][g*5 + q] * H_ + c]);
        hn[q][r][c] = v;
        sh[r][c] += v;
      }
    }
    __syncthreads();
    float acc[5][4];
    #pragma unroll
    for (int q = 0; q < 5; ++q)
      #pragma unroll
      for (int r = 0; r < 4; ++r) acc[q][r] = 0.f;
    for (int k = 0; k < H_; k += 4){
      const float4 w = ld4_(urow + k);
      #pragma unroll
      for (int q = 0; q < 5; ++q){
        #pragma unroll
        for (int r = 0; r < 4; ++r) acc[q][r] += dot4_(w, ld4_(&hn[q][r][k]));
      }
    }
    #pragma unroll
    for (int q = 0; q < 5; ++q){
      #pragma unroll
      for (int r = 0; r < 4; ++r){
        const float rg = sig_(xr[r] + acc[q][r]);
        gated[r] += rg * hn[q][r][c];
      }
    }
    __syncthreads();
  }

  float zg[4];
  {
    const float b = Wzb[c];
    float a0 = b, a1 = b, a2 = b, a3 = b;
    const float* wrow = Wz + (size_t)c * (2 * H_);
    for (int k = 0; k < H_; k += 4){
      const float4 w = ld4_(wrow + k);
      a0 += dot4_(w, ld4_(&xs[0][k]));
      a1 += dot4_(w, ld4_(&xs[1][k]));
      a2 += dot4_(w, ld4_(&xs[2][k]));
      a3 += dot4_(w, ld4_(&xs[3][k]));
    }
    for (int k = 0; k < H_; k += 4){
      const float4 w = ld4_(wrow + H_ + k);
      a0 += dot4_(w, ld4_(&sh[0][k]));
      a1 += dot4_(w, ld4_(&sh[1][k]));
      a2 += dot4_(w, ld4_(&sh[2][k]));
      a3 += dot4_(w, ld4_(&sh[3][k]));
    }
    zg[0] = sig_(a0); zg[1] = sig_(a1); zg[2] = sig_(a2); zg[3] = sig_(a3);
  }

  #pragma unroll
  for (int r = 0; r < 4; ++r) gl[r][c] = gated[r];
  __syncthreads();

  {
    const float b = Whb[c];
    float a0 = b, a1 = b, a2 = b, a3 = b;
    const float* wrow = Wh + (size_t)c * (2 * H_);
    for (int k = 0; k < H_; k += 4){
      const float4 w = ld4_(wrow + k);
      a0 += dot4_(w, ld4_(&xs[0][k]));
      a1 += dot4_(w, ld4_(&xs[1][k]));
      a2 += dot4_(w, ld4_(&xs[2][k]));
      a3 += dot4_(w, ld4_(&xs[3][k]));
    }
    for (int k = 0; k < H_; k += 4){
      const float4 w = ld4_(wrow + H_ + k);
      a0 += dot4_(w, ld4_(&gl[0][k]));
      a1 += dot4_(w, ld4_(&gl[1][k]));
      a2 += dot4_(w, ld4_(&gl[2][k]));
      a3 += dot4_(w, ld4_(&gl[3][k]));
    }
    const float ht[4] = {tanhf(a0), tanhf(a1), tanhf(a2), tanhf(a3)};
    #pragma unroll
    for (int r = 0; r < 4; ++r){
      const float nh = (1.f - zg[r]) * sh[r][c] + zg[r] * ht[r];
      hb16[(size_t)(base + r) * H_ + c] = f2b(nh);
    }
  }
}

// ---- word-prediction head (MFMA): 64 rows/block, 16 rows/wave -------------
__global__ __launch_bounds__(256) void k_pred(
    const u16* __restrict__ hb16, const u16* __restrict__ Ww16,
    const float* __restrict__ Wb, const u16* __restrict__ Wo16,
    const float* __restrict__ Wob, const u16* __restrict__ xt16,
    const int* __restrict__ contexts, const int* __restrict__ pred_targets,
    const int* __restrict__ direction, const int* __restrict__ root_word_ids,
    float* __restrict__ accum)
{
  __shared__ __align__(16) u16 hd[4][16][264];   // relu'd hidden, padded
  __shared__ int   s_tgt[64];
  __shared__ float s_mask[64];
  __shared__ float s_nll[64], s_hit[64], s_msk[64];

  const int tid = threadIdx.x;
  const int p0  = blockIdx.x * 64;
  const int w = tid >> 6, ln = tid & 63, q = ln >> 4, m = ln & 15;
  const int r0 = w * 16;

  if (tid < 64){
    const int p = p0 + tid;
    int tg; float mk;
    if (p < B_){ tg = root_word_ids[p]; mk = 1.f; }
    else { tg = pred_targets[p - B_]; mk = (float)direction[p - B_]; }
    s_tgt[tid] = tg; s_mask[tid] = mk;
  }
  const int p    = p0 + r0 + m;                       // this lane's A-row
  const int hrow = (p < B_) ? E_ : (p - B_);          // root rows -> zero row
  const int ctx  = (p < B_) ? p  : contexts[p - B_];
  __syncthreads();

  // GEMM1: hid = relu([h | xtree] @ Ww^T + Wb)   (K = 384)
  uix4 A1[12];
  {
    const u16* hp = hb16 + (size_t)hrow * 256 + q * 8;
    #pragma unroll
    for (int j = 0; j < 8; ++j) A1[j] = *(const uix4*)(hp + j * 32);
    const u16* xp = xt16 + (size_t)ctx * 128 + q * 8;
    #pragma unroll
    for (int j = 0; j < 4; ++j) A1[8 + j] = *(const uix4*)(xp + j * 32);
  }
  for (int t = 0; t < 16; ++t){
    f32x4 acc = {0.f, 0.f, 0.f, 0.f};
    const u16* bp = Ww16 + (size_t)(t*16 + m) * 384 + q * 8;
    #pragma unroll
    for (int j = 0; j < 12; ++j) acc = mfma16(A1[j], *(const uix4*)(bp + j*32), acc);
    const float bias = Wb[t*16 + m];
    #pragma unroll
    for (int i = 0; i < 4; ++i)
      hd[w][q*4 + i][t*16 + m] = f2b(fmaxf(acc[i] + bias, 0.f));
  }
  __syncthreads();

  // GEMM2: scores = hid @ Wo^T + Wob, online softmax over 800 cols
  uix4 A2[8];
  #pragma unroll
  for (int j = 0; j < 8; ++j) A2[j] = *(const uix4*)(&hd[w][m][j*32 + q*8]);

  int tgtc[4];
  #pragma unroll
  for (int i = 0; i < 4; ++i) tgtc[i] = s_tgt[r0 + q*4 + i];
  float mrun[4], lrun[4], amax[4], tval[4]; int aidx[4];
  #pragma unroll
  for (int i = 0; i < 4; ++i){
    mrun[i] = -1e30f; lrun[i] = 0.f; amax[i] = -1e30f; tval[i] = -1e30f; aidx[i] = 0;
  }

  for (int t = 0; t < 50; ++t){
    f32x4 acc = {0.f, 0.f, 0.f, 0.f};
    const u16* bp = Wo16 + (size_t)(t*16 + m) * 256 + q * 8;
    #pragma unroll
    for (int j = 0; j < 8; ++j) acc = mfma16(A2[j], *(const uix4*)(bp + j*32), acc);
    const int c = t*16 + m;
    const float bias = Wob[c];
    #pragma unroll
    for (int i = 0; i < 4; ++i){
      const float v = acc[i] + bias;
      if (c == tgtc[i]) tval[i] = v;
      if (v > amax[i]){ amax[i] = v; aidx[i] = c; }
      const float nm = fmaxf(mrun[i], v);
      lrun[i] = lrun[i] * __expf(mrun[i] - nm) + __expf(v - nm);
      mrun[i] = nm;
    }
  }
  // merge across the 16 lanes sharing a quad (each holds 50 of the 800 cols)
  #pragma unroll
  for (int msk = 1; msk < 16; msk <<= 1){
    #pragma unroll
    for (int i = 0; i < 4; ++i){
      const float om = __shfl_xor(mrun[i], msk, 64);
      const float ol = __shfl_xor(lrun[i], msk, 64);
      const float nm = fmaxf(mrun[i], om);
      lrun[i] = lrun[i] * __expf(mrun[i] - nm) + ol * __expf(om - nm);
      mrun[i] = nm;
      const float oa = __shfl_xor(amax[i], msk, 64);
      const int   oi = __shfl_xor(aidx[i], msk, 64);
      if (oa > amax[i] || (oa == amax[i] && oi < aidx[i])){ amax[i] = oa; aidx[i] = oi; }
      tval[i] = fmaxf(tval[i], __shfl_xor(tval[i], msk, 64));
    }
  }
  if (m == 0){
    #pragma unroll
    for (int i = 0; i < 4; ++i){
      const int r = r0 + q*4 + i;
      const float mk  = s_mask[r];
      const float nll = mrun[i] + __logf(lrun[i]) - tval[i];
      s_nll[r] = nll * mk;
      s_hit[r] = (aidx[i] == tgtc[i]) ? mk : 0.f;
      s_msk[r] = mk;
    }
  }
  __syncthreads();
  if (tid < 64){
    float a = s_nll[tid], b = s_hit[tid], c2 = s_msk[tid];
    #pragma unroll
    for (int off = 32; off > 0; off >>= 1){
      a += __shfl_down(a, off, 64); b += __shfl_down(b, off, 64); c2 += __shfl_down(c2, off, 64);
    }
    if (tid == 0){
      atomicAdd(&accum[0], a); atomicAdd(&accum[1], b); atomicAdd(&accum[2], c2);
    }
  }
}

// ---- stop head (MFMA): 64 rows/block ---------------------------------------
__global__ __launch_bounds__(256) void k_stop(
    const u16* __restrict__ hb16, const u16* __restrict__ emb16,
    const u16* __restrict__ Ui16, const float* __restrict__ Uib,
    const u16* __restrict__ Uw16, const float* __restrict__ Ub,
    const float* __restrict__ Uo, const float* __restrict__ Uob,
    const u16* __restrict__ xt16,
    const int* __restrict__ word_ids, const int* __restrict__ o_nei,
    const int* __restrict__ contexts, const int* __restrict__ direction,
    const int* __restrict__ root_word_ids, const int* __restrict__ root_o_idx,
    float* __restrict__ accum)
{
  __shared__ __align__(16) u16 so[64][264];   // sum_o, later reused as h1
  __shared__ int   s_oidx[64][NB_];
  __shared__ int   s_wid[64], s_ctx[64];
  __shared__ float s_tgt[64];
  __shared__ float s_b0[64], s_b1[64];

  const int tid = threadIdx.x;
  const int p0  = blockIdx.x * 64;
  const int w = tid >> 6, ln = tid & 63, q = ln >> 4, m = ln & 15;
  const int r0 = w * 16;

  if (tid < 64){
    const int s = p0 + tid;
    if (s < E_){ s_wid[tid] = word_ids[s]; s_ctx[tid] = contexts[s];
                 s_tgt[tid] = (float)direction[s]; }
    else { const int b = s - E_; s_wid[tid] = root_word_ids[b]; s_ctx[tid] = b;
           s_tgt[tid] = 0.f; }
  }
  for (int k = tid; k < 64 * NB_; k += 256){
    const int r = k / NB_, nb = k % NB_;
    const int s = p0 + r;
    s_oidx[r][nb] = (s < E_) ? o_nei[(size_t)s * NB_ + nb]
                             : root_o_idx[(size_t)(s - E_) * NB_ + nb];
  }
  __syncthreads();

  // stage sum_o (final hbuf == per-step value: rows are write-once)
  {
    const int c = tid;
    for (int r = 0; r < 64; ++r){
      float v = 0.f;
      #pragma unroll
      for (int nb = 0; nb < NB_; ++nb)
        v += b2f(hb16[(size_t)s_oidx[r][nb] * 256 + c]);
      so[r][c] = f2b(v);
    }
  }
  __syncthreads();

  // A for GEMM1: [emb | sum_o]  (K = 512)
  uix4 A1[16];
  {
    const u16* ep = emb16 + (size_t)s_wid[r0 + m] * 256 + q * 8;
    #pragma unroll
    for (int j = 0; j < 8; ++j) A1[j] = *(const uix4*)(ep + j * 32);
    #pragma unroll
    for (int j = 0; j < 8; ++j) A1[8 + j] = *(const uix4*)(&so[r0 + m][j*32 + q*8]);
  }
  __syncthreads();   // all waves captured so -> safe to overwrite with h1

  // GEMM1: h1 = relu(inp @ Ui^T + Uib) -> so region (wave-private rows)
  for (int t = 0; t < 16; ++t){
    f32x4 acc = {0.f, 0.f, 0.f, 0.f};
    const u16* bp = Ui16 + (size_t)(t*16 + m) * 512 + q * 8;
    #pragma unroll
    for (int j = 0; j < 16; ++j) acc = mfma16(A1[j], *(const uix4*)(bp + j*32), acc);
    const float bias = Uib[t*16 + m];
    #pragma unroll
    for (int i = 0; i < 4; ++i)
      so[r0 + q*4 + i][t*16 + m] = f2b(fmaxf(acc[i] + bias, 0.f));
  }
  __syncthreads();

  // GEMM2: h2 = relu([h1 | xtree] @ Uw^T + Ub); s = h2 . Uo + Uob
  uix4 A2[12];
  {
    #pragma unroll
    for (int j = 0; j < 8; ++j) A2[j] = *(const uix4*)(&so[r0 + m][j*32 + q*8]);
    const u16* xp = xt16 + (size_t)s_ctx[r0 + m] * 128 + q * 8;
    #pragma unroll
    for (int j = 0; j < 4; ++j) A2[8 + j] = *(const uix4*)(xp + j * 32);
  }
  float sp[4] = {0.f, 0.f, 0.f, 0.f};
  for (int t = 0; t < 16; ++t){
    f32x4 acc = {0.f, 0.f, 0.f, 0.f};
    const u16* bp = Uw16 + (size_t)(t*16 + m) * 384 + q * 8;
    #pragma unroll
    for (int j = 0; j < 12; ++j) acc = mfma16(A2[j], *(const uix4*)(bp + j*32), acc);
    const int c = t*16 + m;
    const float bias = Ub[c];
    const float uo   = Uo[c];
    #pragma unroll
    for (int i = 0; i < 4; ++i) sp[i] += fmaxf(acc[i] + bias, 0.f) * uo;
  }
  #pragma unroll
  for (int msk = 1; msk < 16; msk <<= 1){
    #pragma unroll
    for (int i = 0; i < 4; ++i) sp[i] += __shfl_xor(sp[i], msk, 64);
  }
  if (m == 0){
    const float ub = Uob[0];
    #pragma unroll
    for (int i = 0; i < 4; ++i){
      const int r = r0 + q*4 + i;
      const float s   = sp[i] + ub;
      const float tgt = s_tgt[r];
      s_b0[r] = fmaxf(s, 0.f) - s * tgt + log1pf(__expf(-fabsf(s)));
      const float pb = (s >= 0.f) ? 1.f : 0.f;
      s_b1[r] = (pb == tgt) ? 1.f : 0.f;
    }
  }
  __syncthreads();
  if (tid < 64){
    float a = s_b0[tid], b = s_b1[tid];
    #pragma unroll
    for (int off = 32; off > 0; off >>= 1){
      a += __shfl_down(a, off, 64); b += __shfl_down(b, off, 64);
    }
    if (tid == 0){ atomicAdd(&accum[3], a); atomicAdd(&accum[4], b); }
  }
}

// ---- finalize --------------------------------------------------------------
__global__ void k_final(const float* __restrict__ acc, float* __restrict__ out){
  if (threadIdx.x == 0 && blockIdx.x == 0){
    out[0] = acc[0] / (float)B_;               // pred_loss
    out[1] = acc[3] / (float)B_;               // stop_loss
    out[2] = acc[1] / acc[2];                  // pred_acc
    out[3] = acc[4] / (float)(E_ + B_);        // stop_acc
  }
}

} // anonymous namespace

extern "C" void kernel_launch(void* const* d_in, const int* in_sizes, int n_in,
                              void* d_out, int out_size, void* d_ws, size_t ws_size,
                              hipStream_t stream)
{
  const float* emb   = (const float*)d_in[0];
  const float* Wz    = (const float*)d_in[1];
  const float* Wzb   = (const float*)d_in[2];
  const float* Wr    = (const float*)d_in[3];
  const float* Wrb   = (const float*)d_in[4];
  const float* Ur    = (const float*)d_in[5];
  const float* Wh    = (const float*)d_in[6];
  const float* Whb   = (const float*)d_in[7];
  const float* Ww    = (const float*)d_in[8];
  const float* Wb    = (const float*)d_in[9];
  const float* Wo    = (const float*)d_in[10];
  const float* Wob   = (const float*)d_in[11];
  const float* Uw    = (const float*)d_in[12];
  const float* Ub    = (const float*)d_in[13];
  const float* Ui    = (const float*)d_in[14];
  const float* Uib   = (const float*)d_in[15];
  const float* Uo    = (const float*)d_in[16];
  const float* Uob   = (const float*)d_in[17];
  const float* xtree = (const float*)d_in[18];
  const int* word_ids      = (const int*)d_in[19];
  const int* h_nei_idx     = (const int*)d_in[20];
  const int* o_nei_idx     = (const int*)d_in[21];
  const int* contexts      = (const int*)d_in[22];
  const int* pred_targets  = (const int*)d_in[23];
  const int* direction     = (const int*)d_in[24];
  const int* root_word_ids = (const int*)d_in[25];
  const int* root_o_idx    = (const int*)d_in[26];

  char*  wsb   = (char*)d_ws;
  float* accum = (float*)wsb;
  size_t off = 256;
  u16* hb16  = (u16*)(wsb + off); off += (size_t)(E_ + 1) * H_ * 2;  // 16.78 MB
  u16* emb16 = (u16*)(wsb + off); off += 204800u * 2;
  u16* xt16  = (u16*)(wsb + off); off += 32768u * 2;
  u16* Ww16  = (u16*)(wsb + off); off += 98304u * 2;
  u16* Wo16  = (u16*)(wsb + off); off += 204800u * 2;
  u16* Ui16  = (u16*)(wsb + off); off += 131072u * 2;
  u16* Uw16  = (u16*)(wsb + off); off += 98304u * 2;
  float* out = (float*)d_out;

  hipLaunchKernelGGL(k_cvt, dim3(3008), dim3(256), 0, stream,
                     emb, xtree, Ww, Wo, Ui, Uw,
                     emb16, xt16, Ww16, Wo16, Ui16, Uw16);
  hipLaunchKernelGGL(k_init, dim3(1), dim3(256), 0, stream, accum, hb16);

  for (int t = 0; t < T_; ++t){
    hipLaunchKernelGGL(k_gru, dim3(N_ / 4), dim3(256), 0, stream,
                       emb, Wz, Wzb, Wr, Wrb, Ur, Wh, Whb,
                       word_ids, h_nei_idx, hb16, t);
  }

  hipLaunchKernelGGL(k_pred, dim3((B_ + E_) / 64), dim3(256), 0, stream,
                     hb16, Ww16, Wb, Wo16, Wob, xt16,
                     contexts, pred_targets, direction, root_word_ids, accum);

  hipLaunchKernelGGL(k_stop, dim3((E_ + B_) / 64), dim3(256), 0, stream,
                     hb16, emb16, Ui16, Uib, Uw16, Ub, Uo, Uob, xt16,
                     word_ids, o_nei_idx, contexts, direction,
                     root_word_ids, root_o_idx, accum);

  hipLaunchKernelGGL(k_final, dim3(1), dim3(1), 0, stream, accum, out);
}

// Round 3
// 1847.573 us; speedup vs baseline: 3.3487x; 2.0559x over previous
//
#include <hip/hip_runtime.h>
#include <math.h>

// ---------------------------------------------------------------------------
// JTNN decoder forward on MI355X.  v3: bf16 MFMA everywhere.
//  * GRU scan: 32 step-kernels; block = 16 msg rows / 4 waves (64-col slice
//    each). Ur B-frags register-resident (128 VGPR); neighbor rows staged in
//    LDS (groups of 5, +8 u16 row pad -> 2-way-free banks); r-gate MFMA
//    C-init = xr tile; gated/sum_h accumulated in D-layout registers; one
//    LDS transpose feeds Wz/Wh GEMMs; new_h combined in registers.
//  * hbuf rows write-once -> heads recompute from final hbuf.
//  * k_stop sum_o staging now task-parallel coalesced uix4 gathers.
//  * MFMA layouts (validated in R2): A[m=lane&15][k=32*kb+8*q+j],
//    B[k][n=lane&15], D[row=4*q+i][col=lane&15].
// ---------------------------------------------------------------------------

namespace {

constexpr int T_  = 32;
constexpr int N_  = 1024;
constexpr int H_  = 256;
constexpr int NB_ = 15;
constexpr int E_  = T_ * N_;      // 32768
constexpr int B_  = 256;

typedef unsigned short u16;
typedef unsigned int  uix4  __attribute__((ext_vector_type(4)));
typedef __bf16        bf16x8 __attribute__((ext_vector_type(8)));
typedef float         f32x4  __attribute__((ext_vector_type(4)));

__device__ __forceinline__ float sig_(float x){ return 1.f / (1.f + __expf(-x)); }

__device__ __forceinline__ float b2f(u16 u){
  union { unsigned int i; float f; } v; v.i = ((unsigned int)u) << 16; return v.f;
}
__device__ __forceinline__ u16 f2b(float f){
  union { float f; unsigned int i; } v; v.f = f;
  const unsigned int r = v.i + 0x7fffu + ((v.i >> 16) & 1u);
  return (u16)(r >> 16);
}
__device__ __forceinline__ f32x4 mfma16(uix4 a, uix4 b, f32x4 c){
  return __builtin_amdgcn_mfma_f32_16x16x32_bf16(
      __builtin_bit_cast(bf16x8, a), __builtin_bit_cast(bf16x8, b), c, 0, 0, 0);
}

// ---- fp32 -> bf16 conversion (once per launch) ----------------------------
__global__ __launch_bounds__(256) void k_cvt(
    const float* __restrict__ emb, const float* __restrict__ xt,
    const float* __restrict__ Ww,  const float* __restrict__ Wo,
    const float* __restrict__ Ui,  const float* __restrict__ Uw,
    const float* __restrict__ Wz,  const float* __restrict__ Wr,
    const float* __restrict__ Ur,  const float* __restrict__ Wh,
    u16* __restrict__ o_emb, u16* __restrict__ o_xt, u16* __restrict__ o_Ww,
    u16* __restrict__ o_Wo,  u16* __restrict__ o_Ui, u16* __restrict__ o_Uw,
    u16* __restrict__ o_Wz,  u16* __restrict__ o_Wr, u16* __restrict__ o_Ur,
    u16* __restrict__ o_Wh)
{
  int i = blockIdx.x * 256 + threadIdx.x;
  if (i < 204800){ o_emb[i] = f2b(emb[i]); return; }  i -= 204800;
  if (i <  32768){ o_xt[i]  = f2b(xt[i]);  return; }  i -=  32768;
  if (i <  98304){ o_Ww[i]  = f2b(Ww[i]);  return; }  i -=  98304;
  if (i < 204800){ o_Wo[i]  = f2b(Wo[i]);  return; }  i -= 204800;
  if (i < 131072){ o_Ui[i]  = f2b(Ui[i]);  return; }  i -= 131072;
  if (i <  98304){ o_Uw[i]  = f2b(Uw[i]);  return; }  i -=  98304;
  if (i < 131072){ o_Wz[i]  = f2b(Wz[i]);  return; }  i -= 131072;
  if (i <  65536){ o_Wr[i]  = f2b(Wr[i]);  return; }  i -=  65536;
  if (i <  65536){ o_Ur[i]  = f2b(Ur[i]);  return; }  i -=  65536;
  if (i < 131072){ o_Wh[i]  = f2b(Wh[i]); }
}

// ---- init: zero accumulators + hbuf zero-pad row --------------------------
__global__ __launch_bounds__(256) void k_init(float* __restrict__ acc,
                                              u16* __restrict__ hb16){
  const int tid = threadIdx.x;
  if (tid < 16) acc[tid] = 0.f;
  hb16[(size_t)E_ * H_ + tid] = 0;   // row E = zero pad slot
}

// ---- one GRU scan step (MFMA): 16 rows/block, wave = 64-col slice ---------
__global__ __launch_bounds__(256) void k_gru(
    const u16* __restrict__ emb16,
    const u16* __restrict__ Wz16, const float* __restrict__ Wzb,
    const u16* __restrict__ Wr16, const float* __restrict__ Wrb,
    const u16* __restrict__ Ur16,
    const u16* __restrict__ Wh16, const float* __restrict__ Whb,
    const int* __restrict__ word_ids, const int* __restrict__ h_nei,
    u16* __restrict__ hb16, int t)
{
  __shared__ __align__(16) u16 hn[80 * 264];   // 5 neighbors x 16 rows, padded
  __shared__ __align__(16) u16 sh[16 * 264];   // sum_h   (A-layout)
  __shared__ __align__(16) u16 gl[16 * 264];   // gated   (A-layout)
  __shared__ int s_wid[16];
  __shared__ int s_hidx[16][NB_];

  const int tid = threadIdx.x;
  const int w = tid >> 6, ln = tid & 63, q = ln >> 4, m = ln & 15;
  const int cb   = w * 64;                       // wave's output-col base
  const int base = t * N_ + blockIdx.x * 16;     // first message row

  if (tid < 16) s_wid[tid] = word_ids[base + tid];
  for (int k = tid; k < 16 * NB_; k += 256)
    s_hidx[k / NB_][k % NB_] = h_nei[(base + k / NB_) * NB_ + (k % NB_)];
  __syncthreads();

  // persistent Ur B-frags for this wave's 64 cols (32 x uix4 = 128 VGPR)
  uix4 Bur[32];
  #pragma unroll
  for (int nt = 0; nt < 4; ++nt){
    const u16* bp = Ur16 + (size_t)(cb + nt*16 + m) * 256 + q * 8;
    #pragma unroll
    for (int kb = 0; kb < 8; ++kb) Bur[nt*8 + kb] = *(const uix4*)(bp + kb*32);
  }

  // xr = x @ Wr^T + b_r  (kept as MFMA C-init tiles)
  const u16* xrow = emb16 + (size_t)s_wid[m] * 256 + q * 8;
  f32x4 xr[4];
  {
    uix4 Ax[8];
    #pragma unroll
    for (int kb = 0; kb < 8; ++kb) Ax[kb] = *(const uix4*)(xrow + kb*32);
    #pragma unroll
    for (int nt = 0; nt < 4; ++nt){
      f32x4 a = {0.f, 0.f, 0.f, 0.f};
      const u16* bp = Wr16 + (size_t)(cb + nt*16 + m) * 256 + q * 8;
      #pragma unroll
      for (int kb = 0; kb < 8; ++kb) a = mfma16(Ax[kb], *(const uix4*)(bp + kb*32), a);
      const float bias = Wrb[cb + nt*16 + m];
      #pragma unroll
      for (int i = 0; i < 4; ++i) a[i] += bias;
      xr[nt] = a;
    }
  }

  float ga[4][4], su[4][4];
  #pragma unroll
  for (int nt = 0; nt < 4; ++nt)
    #pragma unroll
    for (int i = 0; i < 4; ++i){ ga[nt][i] = 0.f; su[nt][i] = 0.f; }

  for (int g = 0; g < 3; ++g){
    __syncthreads();                  // prior group fully consumed
    // stage 80 neighbor rows, coalesced 512B per row
    #pragma unroll
    for (int p = 0; p < 10; ++p){
      const int d  = p * 8 + (tid >> 5);          // dest row: nb5*16 + r
      const int ch = tid & 31;                    // 16B chunk
      const int src = s_hidx[d & 15][g*5 + (d >> 4)];
      *(uix4*)(&hn[d*264 + ch*8]) = *(const uix4*)(hb16 + (size_t)src*256 + ch*8);
    }
    __syncthreads();
    for (int nb5 = 0; nb5 < 5; ++nb5){
      uix4 Ah[8];
      #pragma unroll
      for (int kb = 0; kb < 8; ++kb)
        Ah[kb] = *(const uix4*)(&hn[(nb5*16 + m)*264 + kb*32 + q*8]);
      #pragma unroll
      for (int nt = 0; nt < 4; ++nt){
        f32x4 a = xr[nt];             // r-pre = xr + Ur.h via C-init
        #pragma unroll
        for (int kb = 0; kb < 8; ++kb) a = mfma16(Ah[kb], Bur[nt*8 + kb], a);
        #pragma unroll
        for (int i = 0; i < 4; ++i){
          const float hv = b2f(hn[(nb5*16 + q*4 + i)*264 + cb + nt*16 + m]);
          const float rr = sig_(a[i]);
          ga[nt][i] += rr * hv;
          su[nt][i] += hv;
        }
      }
    }
  }

  // transpose sum_h / gated into A-layout LDS (keep su in regs for combine)
  #pragma unroll
  for (int nt = 0; nt < 4; ++nt)
    #pragma unroll
    for (int i = 0; i < 4; ++i){
      sh[(q*4 + i)*264 + cb + nt*16 + m] = f2b(su[nt][i]);
      gl[(q*4 + i)*264 + cb + nt*16 + m] = f2b(ga[nt][i]);
    }
  __syncthreads();

  // z / h~ GEMMs (K = 512 = [x | sh] / [x | gl]), combine, store new_h
  uix4 Ax[8], As[8], Ag[8];
  #pragma unroll
  for (int kb = 0; kb < 8; ++kb){
    Ax[kb] = *(const uix4*)(xrow + kb*32);
    As[kb] = *(const uix4*)(&sh[m*264 + kb*32 + q*8]);
    Ag[kb] = *(const uix4*)(&gl[m*264 + kb*32 + q*8]);
  }
  #pragma unroll
  for (int nt = 0; nt < 4; ++nt){
    const int col = cb + nt*16 + m;
    const u16* bz = Wz16 + (size_t)col * 512 + q * 8;
    f32x4 az = {0.f, 0.f, 0.f, 0.f};
    #pragma unroll
    for (int kb = 0; kb < 8; ++kb) az = mfma16(Ax[kb], *(const uix4*)(bz + kb*32), az);
    #pragma unroll
    for (int kb = 0; kb < 8; ++kb) az = mfma16(As[kb], *(const uix4*)(bz + 256 + kb*32), az);
    const u16* bh = Wh16 + (size_t)col * 512 + q * 8;
    f32x4 ah = {0.f, 0.f, 0.f, 0.f};
    #pragma unroll
    for (int kb = 0; kb < 8; ++kb) ah = mfma16(Ax[kb], *(const uix4*)(bh + kb*32), ah);
    #pragma unroll
    for (int kb = 0; kb < 8; ++kb) ah = mfma16(Ag[kb], *(const uix4*)(bh + 256 + kb*32), ah);
    const float zb = Wzb[col], hb = Whb[col];
    #pragma unroll
    for (int i = 0; i < 4; ++i){
      const float z  = sig_(az[i] + zb);
      const float ht = tanhf(ah[i] + hb);
      const float nh = (1.f - z) * su[nt][i] + z * ht;
      hb16[(size_t)(base + q*4 + i) * 256 + col] = f2b(nh);
    }
  }
}

// ---- word-prediction head (MFMA): 64 rows/block, 16 rows/wave -------------
__global__ __launch_bounds__(256) void k_pred(
    const u16* __restrict__ hb16, const u16* __restrict__ Ww16,
    const float* __restrict__ Wb, const u16* __restrict__ Wo16,
    const float* __restrict__ Wob, const u16* __restrict__ xt16,
    const int* __restrict__ contexts, const int* __restrict__ pred_targets,
    const int* __restrict__ direction, const int* __restrict__ root_word_ids,
    float* __restrict__ accum)
{
  __shared__ __align__(16) u16 hd[4][16][264];   // relu'd hidden, padded
  __shared__ int   s_tgt[64];
  __shared__ float s_mask[64];
  __shared__ float s_nll[64], s_hit[64], s_msk[64];

  const int tid = threadIdx.x;
  const int p0  = blockIdx.x * 64;
  const int w = tid >> 6, ln = tid & 63, q = ln >> 4, m = ln & 15;
  const int r0 = w * 16;

  if (tid < 64){
    const int p = p0 + tid;
    int tg; float mk;
    if (p < B_){ tg = root_word_ids[p]; mk = 1.f; }
    else { tg = pred_targets[p - B_]; mk = (float)direction[p - B_]; }
    s_tgt[tid] = tg; s_mask[tid] = mk;
  }
  const int p    = p0 + r0 + m;
  const int hrow = (p < B_) ? E_ : (p - B_);
  const int ctx  = (p < B_) ? p  : contexts[p - B_];
  __syncthreads();

  // GEMM1: hid = relu([h | xtree] @ Ww^T + Wb)   (K = 384)
  uix4 A1[12];
  {
    const u16* hp = hb16 + (size_t)hrow * 256 + q * 8;
    #pragma unroll
    for (int j = 0; j < 8; ++j) A1[j] = *(const uix4*)(hp + j * 32);
    const u16* xp = xt16 + (size_t)ctx * 128 + q * 8;
    #pragma unroll
    for (int j = 0; j < 4; ++j) A1[8 + j] = *(const uix4*)(xp + j * 32);
  }
  for (int t = 0; t < 16; ++t){
    f32x4 acc = {0.f, 0.f, 0.f, 0.f};
    const u16* bp = Ww16 + (size_t)(t*16 + m) * 384 + q * 8;
    #pragma unroll
    for (int j = 0; j < 12; ++j) acc = mfma16(A1[j], *(const uix4*)(bp + j*32), acc);
    const float bias = Wb[t*16 + m];
    #pragma unroll
    for (int i = 0; i < 4; ++i)
      hd[w][q*4 + i][t*16 + m] = f2b(fmaxf(acc[i] + bias, 0.f));
  }
  __syncthreads();

  // GEMM2: scores = hid @ Wo^T + Wob, online softmax over 800 cols
  uix4 A2[8];
  #pragma unroll
  for (int j = 0; j < 8; ++j) A2[j] = *(const uix4*)(&hd[w][m][j*32 + q*8]);

  int tgtc[4];
  #pragma unroll
  for (int i = 0; i < 4; ++i) tgtc[i] = s_tgt[r0 + q*4 + i];
  float mrun[4], lrun[4], amax[4], tval[4]; int aidx[4];
  #pragma unroll
  for (int i = 0; i < 4; ++i){
    mrun[i] = -1e30f; lrun[i] = 0.f; amax[i] = -1e30f; tval[i] = -1e30f; aidx[i] = 0;
  }

  for (int t = 0; t < 50; ++t){
    f32x4 acc = {0.f, 0.f, 0.f, 0.f};
    const u16* bp = Wo16 + (size_t)(t*16 + m) * 256 + q * 8;
    #pragma unroll
    for (int j = 0; j < 8; ++j) acc = mfma16(A2[j], *(const uix4*)(bp + j*32), acc);
    const int c = t*16 + m;
    const float bias = Wob[c];
    #pragma unroll
    for (int i = 0; i < 4; ++i){
      const float v = acc[i] + bias;
      if (c == tgtc[i]) tval[i] = v;
      if (v > amax[i]){ amax[i] = v; aidx[i] = c; }
      const float nm = fmaxf(mrun[i], v);
      lrun[i] = lrun[i] * __expf(mrun[i] - nm) + __expf(v - nm);
      mrun[i] = nm;
    }
  }
  #pragma unroll
  for (int msk = 1; msk < 16; msk <<= 1){
    #pragma unroll
    for (int i = 0; i < 4; ++i){
      const float om = __shfl_xor(mrun[i], msk, 64);
      const float ol = __shfl_xor(lrun[i], msk, 64);
      const float nm = fmaxf(mrun[i], om);
      lrun[i] = lrun[i] * __expf(mrun[i] - nm) + ol * __expf(om - nm);
      mrun[i] = nm;
      const float oa = __shfl_xor(amax[i], msk, 64);
      const int   oi = __shfl_xor(aidx[i], msk, 64);
      if (oa > amax[i] || (oa == amax[i] && oi < aidx[i])){ amax[i] = oa; aidx[i] = oi; }
      tval[i] = fmaxf(tval[i], __shfl_xor(tval[i], msk, 64));
    }
  }
  if (m == 0){
    #pragma unroll
    for (int i = 0; i < 4; ++i){
      const int r = r0 + q*4 + i;
      const float mk  = s_mask[r];
      const float nll = mrun[i] + __logf(lrun[i]) - tval[i];
      s_nll[r] = nll * mk;
      s_hit[r] = (aidx[i] == tgtc[i]) ? mk : 0.f;
      s_msk[r] = mk;
    }
  }
  __syncthreads();
  if (tid < 64){
    float a = s_nll[tid], b = s_hit[tid], c2 = s_msk[tid];
    #pragma unroll
    for (int off = 32; off > 0; off >>= 1){
      a += __shfl_down(a, off, 64); b += __shfl_down(b, off, 64); c2 += __shfl_down(c2, off, 64);
    }
    if (tid == 0){
      atomicAdd(&accum[0], a); atomicAdd(&accum[1], b); atomicAdd(&accum[2], c2);
    }
  }
}

// ---- stop head (MFMA): 64 rows/block ---------------------------------------
__global__ __launch_bounds__(256) void k_stop(
    const u16* __restrict__ hb16, const u16* __restrict__ emb16,
    const u16* __restrict__ Ui16, const float* __restrict__ Uib,
    const u16* __restrict__ Uw16, const float* __restrict__ Ub,
    const float* __restrict__ Uo, const float* __restrict__ Uob,
    const u16* __restrict__ xt16,
    const int* __restrict__ word_ids, const int* __restrict__ o_nei,
    const int* __restrict__ contexts, const int* __restrict__ direction,
    const int* __restrict__ root_word_ids, const int* __restrict__ root_o_idx,
    float* __restrict__ accum)
{
  __shared__ __align__(16) u16 so[64][264];   // sum_o, later reused as h1
  __shared__ int   s_oidx[64][NB_];
  __shared__ int   s_wid[64], s_ctx[64];
  __shared__ float s_tgt[64];
  __shared__ float s_b0[64], s_b1[64];

  const int tid = threadIdx.x;
  const int p0  = blockIdx.x * 64;
  const int w = tid >> 6, ln = tid & 63, q = ln >> 4, m = ln & 15;
  const int r0 = w * 16;

  if (tid < 64){
    const int s = p0 + tid;
    if (s < E_){ s_wid[tid] = word_ids[s]; s_ctx[tid] = contexts[s];
                 s_tgt[tid] = (float)direction[s]; }
    else { const int b = s - E_; s_wid[tid] = root_word_ids[b]; s_ctx[tid] = b;
           s_tgt[tid] = 0.f; }
  }
  for (int k = tid; k < 64 * NB_; k += 256){
    const int r = k / NB_, nb = k % NB_;
    const int s = p0 + r;
    s_oidx[r][nb] = (s < E_) ? o_nei[(size_t)s * NB_ + nb]
                             : root_o_idx[(size_t)(s - E_) * NB_ + nb];
  }
  __syncthreads();

  // stage sum_o: task-parallel (row, 16-col slice), coalesced uix4 gathers
  for (int it = 0; it < 4; ++it){
    const int task = it * 256 + tid;
    const int row = task >> 4, sl = task & 15;
    float a[16];
    #pragma unroll
    for (int c = 0; c < 16; ++c) a[c] = 0.f;
    #pragma unroll
    for (int nb = 0; nb < NB_; ++nb){
      const u16* p = hb16 + (size_t)s_oidx[row][nb] * 256 + sl * 16;
      const uix4 v0 = *(const uix4*)(p);
      const uix4 v1 = *(const uix4*)(p + 8);
      #pragma unroll
      for (int c = 0; c < 4; ++c){
        a[2*c]     += b2f((u16)(v0[c] & 0xffffu));
        a[2*c + 1] += b2f((u16)(v0[c] >> 16));
        a[8 + 2*c] += b2f((u16)(v1[c] & 0xffffu));
        a[9 + 2*c] += b2f((u16)(v1[c] >> 16));
      }
    }
    uix4 o0, o1;
    #pragma unroll
    for (int c = 0; c < 4; ++c){
      o0[c] = (unsigned)f2b(a[2*c])   | ((unsigned)f2b(a[2*c+1]) << 16);
      o1[c] = (unsigned)f2b(a[8+2*c]) | ((unsigned)f2b(a[9+2*c]) << 16);
    }
    *(uix4*)(&so[row][sl*16])     = o0;
    *(uix4*)(&so[row][sl*16 + 8]) = o1;
  }
  __syncthreads();

  // A for GEMM1: [emb | sum_o]  (K = 512)
  uix4 A1[16];
  {
    const u16* ep = emb16 + (size_t)s_wid[r0 + m] * 256 + q * 8;
    #pragma unroll
    for (int j = 0; j < 8; ++j) A1[j] = *(const uix4*)(ep + j * 32);
    #pragma unroll
    for (int j = 0; j < 8; ++j) A1[8 + j] = *(const uix4*)(&so[r0 + m][j*32 + q*8]);
  }
  __syncthreads();   // all waves captured so -> safe to overwrite with h1

  // GEMM1: h1 = relu(inp @ Ui^T + Uib) -> so region (wave-private rows)
  for (int t = 0; t < 16; ++t){
    f32x4 acc = {0.f, 0.f, 0.f, 0.f};
    const u16* bp = Ui16 + (size_t)(t*16 + m) * 512 + q * 8;
    #pragma unroll
    for (int j = 0; j < 16; ++j) acc = mfma16(A1[j], *(const uix4*)(bp + j*32), acc);
    const float bias = Uib[t*16 + m];
    #pragma unroll
    for (int i = 0; i < 4; ++i)
      so[r0 + q*4 + i][t*16 + m] = f2b(fmaxf(acc[i] + bias, 0.f));
  }
  __syncthreads();

  // GEMM2: h2 = relu([h1 | xtree] @ Uw^T + Ub); s = h2 . Uo + Uob
  uix4 A2[12];
  {
    #pragma unroll
    for (int j = 0; j < 8; ++j) A2[j] = *(const uix4*)(&so[r0 + m][j*32 + q*8]);
    const u16* xp = xt16 + (size_t)s_ctx[r0 + m] * 128 + q * 8;
    #pragma unroll
    for (int j = 0; j < 4; ++j) A2[8 + j] = *(const uix4*)(xp + j * 32);
  }
  float sp[4] = {0.f, 0.f, 0.f, 0.f};
  for (int t = 0; t < 16; ++t){
    f32x4 acc = {0.f, 0.f, 0.f, 0.f};
    const u16* bp = Uw16 + (size_t)(t*16 + m) * 384 + q * 8;
    #pragma unroll
    for (int j = 0; j < 12; ++j) acc = mfma16(A2[j], *(const uix4*)(bp + j*32), acc);
    const int c = t*16 + m;
    const float bias = Ub[c];
    const float uo   = Uo[c];
    #pragma unroll
    for (int i = 0; i < 4; ++i) sp[i] += fmaxf(acc[i] + bias, 0.f) * uo;
  }
  #pragma unroll
  for (int msk = 1; msk < 16; msk <<= 1){
    #pragma unroll
    for (int i = 0; i < 4; ++i) sp[i] += __shfl_xor(sp[i], msk, 64);
  }
  if (m == 0){
    const float ub = Uob[0];
    #pragma unroll
    for (int i = 0; i < 4; ++i){
      const int r = r0 + q*4 + i;
      const float s   = sp[i] + ub;
      const float tgt = s_tgt[r];
      s_b0[r] = fmaxf(s, 0.f) - s * tgt + log1pf(__expf(-fabsf(s)));
      const float pb = (s >= 0.f) ? 1.f : 0.f;
      s_b1[r] = (pb == tgt) ? 1.f : 0.f;
    }
  }
  __syncthreads();
  if (tid < 64){
    float a = s_b0[tid], b = s_b1[tid];
    #pragma unroll
    for (int off = 32; off > 0; off >>= 1){
      a += __shfl_down(a, off, 64); b += __shfl_down(b, off, 64);
    }
    if (tid == 0){ atomicAdd(&accum[3], a); atomicAdd(&accum[4], b); }
  }
}

// ---- finalize --------------------------------------------------------------
__global__ void k_final(const float* __restrict__ acc, float* __restrict__ out){
  if (threadIdx.x == 0 && blockIdx.x == 0){
    out[0] = acc[0] / (float)B_;               // pred_loss
    out[1] = acc[3] / (float)B_;               // stop_loss
    out[2] = acc[1] / acc[2];                  // pred_acc
    out[3] = acc[4] / (float)(E_ + B_);        // stop_acc
  }
}

} // anonymous namespace

extern "C" void kernel_launch(void* const* d_in, const int* in_sizes, int n_in,
                              void* d_out, int out_size, void* d_ws, size_t ws_size,
                              hipStream_t stream)
{
  const float* emb   = (const float*)d_in[0];
  const float* Wz    = (const float*)d_in[1];
  const float* Wzb   = (const float*)d_in[2];
  const float* Wr    = (const float*)d_in[3];
  const float* Wrb   = (const float*)d_in[4];
  const float* Ur    = (const float*)d_in[5];
  const float* Wh    = (const float*)d_in[6];
  const float* Whb   = (const float*)d_in[7];
  const float* Ww    = (const float*)d_in[8];
  const float* Wb    = (const float*)d_in[9];
  const float* Wo    = (const float*)d_in[10];
  const float* Wob   = (const float*)d_in[11];
  const float* Uw    = (const float*)d_in[12];
  const float* Ub    = (const float*)d_in[13];
  const float* Ui    = (const float*)d_in[14];
  const float* Uib   = (const float*)d_in[15];
  const float* Uo    = (const float*)d_in[16];
  const float* Uob   = (const float*)d_in[17];
  const float* xtree = (const float*)d_in[18];
  const int* word_ids      = (const int*)d_in[19];
  const int* h_nei_idx     = (const int*)d_in[20];
  const int* o_nei_idx     = (const int*)d_in[21];
  const int* contexts      = (const int*)d_in[22];
  const int* pred_targets  = (const int*)d_in[23];
  const int* direction     = (const int*)d_in[24];
  const int* root_word_ids = (const int*)d_in[25];
  const int* root_o_idx    = (const int*)d_in[26];

  char*  wsb   = (char*)d_ws;
  float* accum = (float*)wsb;
  size_t off = 256;
  u16* hb16  = (u16*)(wsb + off); off += (size_t)(E_ + 1) * H_ * 2;  // 16.78 MB
  u16* emb16 = (u16*)(wsb + off); off += 204800u * 2;
  u16* xt16  = (u16*)(wsb + off); off += 32768u * 2;
  u16* Ww16  = (u16*)(wsb + off); off += 98304u * 2;
  u16* Wo16  = (u16*)(wsb + off); off += 204800u * 2;
  u16* Ui16  = (u16*)(wsb + off); off += 131072u * 2;
  u16* Uw16  = (u16*)(wsb + off); off += 98304u * 2;
  u16* Wz16  = (u16*)(wsb + off); off += 131072u * 2;
  u16* Wr16  = (u16*)(wsb + off); off += 65536u * 2;
  u16* Ur16  = (u16*)(wsb + off); off += 65536u * 2;
  u16* Wh16  = (u16*)(wsb + off); off += 131072u * 2;
  float* out = (float*)d_out;

  hipLaunchKernelGGL(k_cvt, dim3(4544), dim3(256), 0, stream,
                     emb, xtree, Ww, Wo, Ui, Uw, Wz, Wr, Ur, Wh,
                     emb16, xt16, Ww16, Wo16, Ui16, Uw16,
                     Wz16, Wr16, Ur16, Wh16);
  hipLaunchKernelGGL(k_init, dim3(1), dim3(256), 0, stream, accum, hb16);

  for (int t = 0; t < T_; ++t){
    hipLaunchKernelGGL(k_gru, dim3(N_ / 16), dim3(256), 0, stream,
                       emb16, Wz16, Wzb, Wr16, Wrb, Ur16, Wh16, Whb,
                       word_ids, h_nei_idx, hb16, t);
  }

  hipLaunchKernelGGL(k_pred, dim3((B_ + E_) / 64), dim3(256), 0, stream,
                     hb16, Ww16, Wb, Wo16, Wob, xt16,
                     contexts, pred_targets, direction, root_word_ids, accum);

  hipLaunchKernelGGL(k_stop, dim3((E_ + B_) / 64), dim3(256), 0, stream,
                     hb16, emb16, Ui16, Uib, Uw16, Ub, Uo, Uob, xt16,
                     word_ids, o_nei_idx, contexts, direction,
                     root_word_ids, root_o_idx, accum);

  hipLaunchKernelGGL(k_final, dim3(1), dim3(1), 0, stream, accum, out);
}

// Round 4
// 1441.068 us; speedup vs baseline: 4.2933x; 1.2821x over previous
//
#include <hip/hip_runtime.h>
#include <math.h>

// ---------------------------------------------------------------------------
// JTNN decoder forward on MI355X.  v4:
//  * k_gru: 4 msg rows/block, grid 256 (full CU coverage). r-gate GEMM packs
//    (row,nb) pairs 16/tile with pair=nb*4+row -> D row 4q+i maps to
//    (msg row=i, nb=4j+q); quad shfl_xor(16/32) reduces ga/su; nb=15 pad row
//    = hbuf row E (zeros) contributes 0. All 15 neighbors staged at once.
//  * k_pred/k_stop: register-prefetch of next B tile inside the GEMM2 loops
//    (hide L2 latency).
//  * hbuf rows write-once -> heads recompute from final hbuf.
//  * MFMA layouts (validated R2/R3): A[m=lane&15][k=32*kb+8*q+j],
//    B[k][n=lane&15], D[row=4*q+i][col=lane&15].
// ---------------------------------------------------------------------------

namespace {

constexpr int T_  = 32;
constexpr int N_  = 1024;
constexpr int H_  = 256;
constexpr int NB_ = 15;
constexpr int E_  = T_ * N_;      // 32768
constexpr int B_  = 256;

typedef unsigned short u16;
typedef unsigned int  uix4  __attribute__((ext_vector_type(4)));
typedef __bf16        bf16x8 __attribute__((ext_vector_type(8)));
typedef float         f32x4  __attribute__((ext_vector_type(4)));

__device__ __forceinline__ float sig_(float x){ return 1.f / (1.f + __expf(-x)); }

__device__ __forceinline__ float b2f(u16 u){
  union { unsigned int i; float f; } v; v.i = ((unsigned int)u) << 16; return v.f;
}
__device__ __forceinline__ u16 f2b(float f){
  union { float f; unsigned int i; } v; v.f = f;
  const unsigned int r = v.i + 0x7fffu + ((v.i >> 16) & 1u);
  return (u16)(r >> 16);
}
__device__ __forceinline__ f32x4 mfma16(uix4 a, uix4 b, f32x4 c){
  return __builtin_amdgcn_mfma_f32_16x16x32_bf16(
      __builtin_bit_cast(bf16x8, a), __builtin_bit_cast(bf16x8, b), c, 0, 0, 0);
}

// ---- fp32 -> bf16 conversion (once per launch) ----------------------------
__global__ __launch_bounds__(256) void k_cvt(
    const float* __restrict__ emb, const float* __restrict__ xt,
    const float* __restrict__ Ww,  const float* __restrict__ Wo,
    const float* __restrict__ Ui,  const float* __restrict__ Uw,
    const float* __restrict__ Wz,  const float* __restrict__ Wr,
    const float* __restrict__ Ur,  const float* __restrict__ Wh,
    u16* __restrict__ o_emb, u16* __restrict__ o_xt, u16* __restrict__ o_Ww,
    u16* __restrict__ o_Wo,  u16* __restrict__ o_Ui, u16* __restrict__ o_Uw,
    u16* __restrict__ o_Wz,  u16* __restrict__ o_Wr, u16* __restrict__ o_Ur,
    u16* __restrict__ o_Wh)
{
  int i = blockIdx.x * 256 + threadIdx.x;
  if (i < 204800){ o_emb[i] = f2b(emb[i]); return; }  i -= 204800;
  if (i <  32768){ o_xt[i]  = f2b(xt[i]);  return; }  i -=  32768;
  if (i <  98304){ o_Ww[i]  = f2b(Ww[i]);  return; }  i -=  98304;
  if (i < 204800){ o_Wo[i]  = f2b(Wo[i]);  return; }  i -= 204800;
  if (i < 131072){ o_Ui[i]  = f2b(Ui[i]);  return; }  i -= 131072;
  if (i <  98304){ o_Uw[i]  = f2b(Uw[i]);  return; }  i -=  98304;
  if (i < 131072){ o_Wz[i]  = f2b(Wz[i]);  return; }  i -= 131072;
  if (i <  65536){ o_Wr[i]  = f2b(Wr[i]);  return; }  i -=  65536;
  if (i <  65536){ o_Ur[i]  = f2b(Ur[i]);  return; }  i -=  65536;
  if (i < 131072){ o_Wh[i]  = f2b(Wh[i]); }
}

// ---- init: zero accumulators + hbuf zero-pad row --------------------------
__global__ __launch_bounds__(256) void k_init(float* __restrict__ acc,
                                              u16* __restrict__ hb16){
  const int tid = threadIdx.x;
  if (tid < 16) acc[tid] = 0.f;
  hb16[(size_t)E_ * H_ + tid] = 0;   // row E = zero pad slot
}

// ---- one GRU scan step (MFMA): 4 rows/block, grid 256 ---------------------
// wave = 64-col slice; (row,nb) pairs packed 16/A-tile, pair = nb*4 + row.
__global__ __launch_bounds__(256, 1) void k_gru(
    const u16* __restrict__ emb16,
    const u16* __restrict__ Wz16, const float* __restrict__ Wzb,
    const u16* __restrict__ Wr16, const float* __restrict__ Wrb,
    const u16* __restrict__ Ur16,
    const u16* __restrict__ Wh16, const float* __restrict__ Whb,
    const int* __restrict__ word_ids, const int* __restrict__ h_nei,
    u16* __restrict__ hb16, int t)
{
  __shared__ __align__(16) u16 hn[64 * 264];   // 64 (row,nb) pairs, padded
  __shared__ __align__(16) u16 xs[4][264];     // embedding rows
  __shared__ __align__(16) u16 sh[4][264];     // sum_h (A-layout)
  __shared__ __align__(16) u16 gl[4][264];     // gated (A-layout)
  __shared__ int s_wid[4];
  __shared__ int s_hidx[64];                    // pair p = nb*4 + row

  const int tid = threadIdx.x;
  const int w = tid >> 6, ln = tid & 63, q = ln >> 4, m = ln & 15;
  const int cb   = w * 64;                      // wave's output-col base
  const int base = t * N_ + blockIdx.x * 4;     // first message row

  if (tid < 4) s_wid[tid] = word_ids[base + tid];
  if (tid < 64){
    const int row = tid & 3, nb = tid >> 2;
    s_hidx[tid] = (nb < NB_) ? h_nei[(base + row) * NB_ + nb] : E_;
  }
  __syncthreads();

  // stage 64 pair-rows (512B coalesced each) + 4 embedding rows
  #pragma unroll
  for (int it = 0; it < 8; ++it){
    const int task = it * 256 + tid;
    const int row = task >> 5, ch = task & 31;
    *(uix4*)(&hn[row*264 + ch*8]) =
        *(const uix4*)(hb16 + (size_t)s_hidx[row]*256 + ch*8);
  }
  if (tid < 128){
    const int row = tid >> 5, ch = tid & 31;
    *(uix4*)(&xs[row][ch*8]) =
        *(const uix4*)(emb16 + (size_t)s_wid[row]*256 + ch*8);
  }
  __syncthreads();

  // A-frag of x (rows replicated m&3)
  uix4 Ax[8];
  #pragma unroll
  for (int kb = 0; kb < 8; ++kb) Ax[kb] = *(const uix4*)(&xs[m & 3][kb*32 + q*8]);

  // xr = x @ Wr^T + b_r  (C-init tiles; D row 4q+i == message i)
  f32x4 xr[4];
  #pragma unroll
  for (int nt = 0; nt < 4; ++nt){
    const int col = cb + nt*16 + m;
    f32x4 a = {0.f, 0.f, 0.f, 0.f};
    const u16* bp = Wr16 + (size_t)col * 256 + q * 8;
    #pragma unroll
    for (int kb = 0; kb < 8; ++kb) a = mfma16(Ax[kb], *(const uix4*)(bp + kb*32), a);
    const float bias = Wrb[col];
    #pragma unroll
    for (int i = 0; i < 4; ++i) a[i] += bias;
    xr[nt] = a;
  }

  // persistent Ur B-frags (64 cols x K256 = 32 uix4)
  uix4 Bur[32];
  #pragma unroll
  for (int nt = 0; nt < 4; ++nt){
    const u16* bp = Ur16 + (size_t)(cb + nt*16 + m) * 256 + q * 8;
    #pragma unroll
    for (int kb = 0; kb < 8; ++kb) Bur[nt*8 + kb] = *(const uix4*)(bp + kb*32);
  }

  // r-gate GEMM over 4 pair-tiles; extract ga/su per (msg row=i, nb=4j+q)
  float ga[4][4], su[4][4];
  #pragma unroll
  for (int nt = 0; nt < 4; ++nt)
    #pragma unroll
    for (int i = 0; i < 4; ++i){ ga[nt][i] = 0.f; su[nt][i] = 0.f; }

  #pragma unroll
  for (int j = 0; j < 4; ++j){
    uix4 Ah[8];
    #pragma unroll
    for (int kb = 0; kb < 8; ++kb)
      Ah[kb] = *(const uix4*)(&hn[(j*16 + m)*264 + kb*32 + q*8]);
    #pragma unroll
    for (int nt = 0; nt < 4; ++nt){
      f32x4 a = xr[nt];
      #pragma unroll
      for (int kb = 0; kb < 8; ++kb) a = mfma16(Ah[kb], Bur[nt*8 + kb], a);
      #pragma unroll
      for (int i = 0; i < 4; ++i){
        const float hv = b2f(hn[(j*16 + 4*q + i)*264 + cb + nt*16 + m]);
        ga[nt][i] += sig_(a[i]) * hv;
        su[nt][i] += hv;
      }
    }
  }

  // reduce over nb partition (quads): nb = 4j+q -> sum over q
  #pragma unroll
  for (int nt = 0; nt < 4; ++nt)
    #pragma unroll
    for (int i = 0; i < 4; ++i){
      ga[nt][i] += __shfl_xor(ga[nt][i], 16, 64);
      ga[nt][i] += __shfl_xor(ga[nt][i], 32, 64);
      su[nt][i] += __shfl_xor(su[nt][i], 16, 64);
      su[nt][i] += __shfl_xor(su[nt][i], 32, 64);
    }
  if (q == 0){
    #pragma unroll
    for (int nt = 0; nt < 4; ++nt)
      #pragma unroll
      for (int i = 0; i < 4; ++i){
        sh[i][cb + nt*16 + m] = f2b(su[nt][i]);
        gl[i][cb + nt*16 + m] = f2b(ga[nt][i]);
      }
  }
  __syncthreads();

  // z / h~ GEMMs (K=512), combine, store (q==0 lanes own real rows 0..3)
  uix4 As[8], Ag[8];
  #pragma unroll
  for (int kb = 0; kb < 8; ++kb){
    As[kb] = *(const uix4*)(&sh[m & 3][kb*32 + q*8]);
    Ag[kb] = *(const uix4*)(&gl[m & 3][kb*32 + q*8]);
  }
  #pragma unroll
  for (int nt = 0; nt < 4; ++nt){
    const int col = cb + nt*16 + m;
    const u16* bz = Wz16 + (size_t)col * 512 + q * 8;
    f32x4 az = {0.f, 0.f, 0.f, 0.f};
    #pragma unroll
    for (int kb = 0; kb < 8; ++kb) az = mfma16(Ax[kb], *(const uix4*)(bz + kb*32), az);
    #pragma unroll
    for (int kb = 0; kb < 8; ++kb) az = mfma16(As[kb], *(const uix4*)(bz + 256 + kb*32), az);
    const u16* bh = Wh16 + (size_t)col * 512 + q * 8;
    f32x4 ah = {0.f, 0.f, 0.f, 0.f};
    #pragma unroll
    for (int kb = 0; kb < 8; ++kb) ah = mfma16(Ax[kb], *(const uix4*)(bh + kb*32), ah);
    #pragma unroll
    for (int kb = 0; kb < 8; ++kb) ah = mfma16(Ag[kb], *(const uix4*)(bh + 256 + kb*32), ah);
    if (q == 0){
      const float zb = Wzb[col], hb = Whb[col];
      #pragma unroll
      for (int i = 0; i < 4; ++i){
        const float z  = sig_(az[i] + zb);
        const float ht = tanhf(ah[i] + hb);
        const float nh = (1.f - z) * su[nt][i] + z * ht;
        hb16[(size_t)(base + i) * 256 + col] = f2b(nh);
      }
    }
  }
}

// ---- word-prediction head (MFMA): 64 rows/block, 16 rows/wave -------------
__global__ __launch_bounds__(256) void k_pred(
    const u16* __restrict__ hb16, const u16* __restrict__ Ww16,
    const float* __restrict__ Wb, const u16* __restrict__ Wo16,
    const float* __restrict__ Wob, const u16* __restrict__ xt16,
    const int* __restrict__ contexts, const int* __restrict__ pred_targets,
    const int* __restrict__ direction, const int* __restrict__ root_word_ids,
    float* __restrict__ accum)
{
  __shared__ __align__(16) u16 hd[4][16][264];
  __shared__ int   s_tgt[64];
  __shared__ float s_mask[64];
  __shared__ float s_nll[64], s_hit[64], s_msk[64];

  const int tid = threadIdx.x;
  const int p0  = blockIdx.x * 64;
  const int w = tid >> 6, ln = tid & 63, q = ln >> 4, m = ln & 15;
  const int r0 = w * 16;

  if (tid < 64){
    const int p = p0 + tid;
    int tg; float mk;
    if (p < B_){ tg = root_word_ids[p]; mk = 1.f; }
    else { tg = pred_targets[p - B_]; mk = (float)direction[p - B_]; }
    s_tgt[tid] = tg; s_mask[tid] = mk;
  }
  const int p    = p0 + r0 + m;
  const int hrow = (p < B_) ? E_ : (p - B_);
  const int ctx  = (p < B_) ? p  : contexts[p - B_];
  __syncthreads();

  // GEMM1: hid = relu([h | xtree] @ Ww^T + Wb)   (K = 384)
  uix4 A1[12];
  {
    const u16* hp = hb16 + (size_t)hrow * 256 + q * 8;
    #pragma unroll
    for (int j = 0; j < 8; ++j) A1[j] = *(const uix4*)(hp + j * 32);
    const u16* xp = xt16 + (size_t)ctx * 128 + q * 8;
    #pragma unroll
    for (int j = 0; j < 4; ++j) A1[8 + j] = *(const uix4*)(xp + j * 32);
  }
  for (int t = 0; t < 16; ++t){
    f32x4 acc = {0.f, 0.f, 0.f, 0.f};
    const u16* bp = Ww16 + (size_t)(t*16 + m) * 384 + q * 8;
    #pragma unroll
    for (int j = 0; j < 12; ++j) acc = mfma16(A1[j], *(const uix4*)(bp + j*32), acc);
    const float bias = Wb[t*16 + m];
    #pragma unroll
    for (int i = 0; i < 4; ++i)
      hd[w][q*4 + i][t*16 + m] = f2b(fmaxf(acc[i] + bias, 0.f));
  }
  __syncthreads();

  // GEMM2: scores = hid @ Wo^T + Wob, online softmax, B-prefetch pipeline
  uix4 A2[8];
  #pragma unroll
  for (int j = 0; j < 8; ++j) A2[j] = *(const uix4*)(&hd[w][m][j*32 + q*8]);

  int tgtc[4];
  #pragma unroll
  for (int i = 0; i < 4; ++i) tgtc[i] = s_tgt[r0 + q*4 + i];
  float mrun[4], lrun[4], amax[4], tval[4]; int aidx[4];
  #pragma unroll
  for (int i = 0; i < 4; ++i){
    mrun[i] = -1e30f; lrun[i] = 0.f; amax[i] = -1e30f; tval[i] = -1e30f; aidx[i] = 0;
  }

  uix4 Bf[8];
  {
    const u16* bp = Wo16 + (size_t)m * 256 + q * 8;
    #pragma unroll
    for (int j = 0; j < 8; ++j) Bf[j] = *(const uix4*)(bp + j*32);
  }
  for (int t = 0; t < 50; ++t){
    uix4 Bn[8];
    if (t < 49){
      const u16* bp = Wo16 + (size_t)((t+1)*16 + m) * 256 + q * 8;
      #pragma unroll
      for (int j = 0; j < 8; ++j) Bn[j] = *(const uix4*)(bp + j*32);
    } else {
      #pragma unroll
      for (int j = 0; j < 8; ++j) Bn[j] = Bf[j];
    }
    f32x4 acc = {0.f, 0.f, 0.f, 0.f};
    #pragma unroll
    for (int j = 0; j < 8; ++j) acc = mfma16(A2[j], Bf[j], acc);
    const int c = t*16 + m;
    const float bias = Wob[c];
    #pragma unroll
    for (int i = 0; i < 4; ++i){
      const float v = acc[i] + bias;
      if (c == tgtc[i]) tval[i] = v;
      if (v > amax[i]){ amax[i] = v; aidx[i] = c; }
      const float nm = fmaxf(mrun[i], v);
      lrun[i] = lrun[i] * __expf(mrun[i] - nm) + __expf(v - nm);
      mrun[i] = nm;
    }
    #pragma unroll
    for (int j = 0; j < 8; ++j) Bf[j] = Bn[j];
  }
  #pragma unroll
  for (int msk = 1; msk < 16; msk <<= 1){
    #pragma unroll
    for (int i = 0; i < 4; ++i){
      const float om = __shfl_xor(mrun[i], msk, 64);
      const float ol = __shfl_xor(lrun[i], msk, 64);
      const float nm = fmaxf(mrun[i], om);
      lrun[i] = lrun[i] * __expf(mrun[i] - nm) + ol * __expf(om - nm);
      mrun[i] = nm;
      const float oa = __shfl_xor(amax[i], msk, 64);
      const int   oi = __shfl_xor(aidx[i], msk, 64);
      if (oa > amax[i] || (oa == amax[i] && oi < aidx[i])){ amax[i] = oa; aidx[i] = oi; }
      tval[i] = fmaxf(tval[i], __shfl_xor(tval[i], msk, 64));
    }
  }
  if (m == 0){
    #pragma unroll
    for (int i = 0; i < 4; ++i){
      const int r = r0 + q*4 + i;
      const float mk  = s_mask[r];
      const float nll = mrun[i] + __logf(lrun[i]) - tval[i];
      s_nll[r] = nll * mk;
      s_hit[r] = (aidx[i] == tgtc[i]) ? mk : 0.f;
      s_msk[r] = mk;
    }
  }
  __syncthreads();
  if (tid < 64){
    float a = s_nll[tid], b = s_hit[tid], c2 = s_msk[tid];
    #pragma unroll
    for (int off = 32; off > 0; off >>= 1){
      a += __shfl_down(a, off, 64); b += __shfl_down(b, off, 64); c2 += __shfl_down(c2, off, 64);
    }
    if (tid == 0){
      atomicAdd(&accum[0], a); atomicAdd(&accum[1], b); atomicAdd(&accum[2], c2);
    }
  }
}

// ---- stop head (MFMA): 64 rows/block ---------------------------------------
__global__ __launch_bounds__(256) void k_stop(
    const u16* __restrict__ hb16, const u16* __restrict__ emb16,
    const u16* __restrict__ Ui16, const float* __restrict__ Uib,
    const u16* __restrict__ Uw16, const float* __restrict__ Ub,
    const float* __restrict__ Uo, const float* __restrict__ Uob,
    const u16* __restrict__ xt16,
    const int* __restrict__ word_ids, const int* __restrict__ o_nei,
    const int* __restrict__ contexts, const int* __restrict__ direction,
    const int* __restrict__ root_word_ids, const int* __restrict__ root_o_idx,
    float* __restrict__ accum)
{
  __shared__ __align__(16) u16 so[64][264];   // sum_o, later reused as h1
  __shared__ int   s_oidx[64][NB_];
  __shared__ int   s_wid[64], s_ctx[64];
  __shared__ float s_tgt[64];
  __shared__ float s_b0[64], s_b1[64];

  const int tid = threadIdx.x;
  const int p0  = blockIdx.x * 64;
  const int w = tid >> 6, ln = tid & 63, q = ln >> 4, m = ln & 15;
  const int r0 = w * 16;

  if (tid < 64){
    const int s = p0 + tid;
    if (s < E_){ s_wid[tid] = word_ids[s]; s_ctx[tid] = contexts[s];
                 s_tgt[tid] = (float)direction[s]; }
    else { const int b = s - E_; s_wid[tid] = root_word_ids[b]; s_ctx[tid] = b;
           s_tgt[tid] = 0.f; }
  }
  for (int k = tid; k < 64 * NB_; k += 256){
    const int r = k / NB_, nb = k % NB_;
    const int s = p0 + r;
    s_oidx[r][nb] = (s < E_) ? o_nei[(size_t)s * NB_ + nb]
                             : root_o_idx[(size_t)(s - E_) * NB_ + nb];
  }
  __syncthreads();

  // stage sum_o: task-parallel (row, 16-col slice), coalesced uix4 gathers
  for (int it = 0; it < 4; ++it){
    const int task = it * 256 + tid;
    const int row = task >> 4, sl = task & 15;
    float a[16];
    #pragma unroll
    for (int c = 0; c < 16; ++c) a[c] = 0.f;
    #pragma unroll
    for (int nb = 0; nb < NB_; ++nb){
      const u16* p = hb16 + (size_t)s_oidx[row][nb] * 256 + sl * 16;
      const uix4 v0 = *(const uix4*)(p);
      const uix4 v1 = *(const uix4*)(p + 8);
      #pragma unroll
      for (int c = 0; c < 4; ++c){
        a[2*c]     += b2f((u16)(v0[c] & 0xffffu));
        a[2*c + 1] += b2f((u16)(v0[c] >> 16));
        a[8 + 2*c] += b2f((u16)(v1[c] & 0xffffu));
        a[9 + 2*c] += b2f((u16)(v1[c] >> 16));
      }
    }
    uix4 o0, o1;
    #pragma unroll
    for (int c = 0; c < 4; ++c){
      o0[c] = (unsigned)f2b(a[2*c])   | ((unsigned)f2b(a[2*c+1]) << 16);
      o1[c] = (unsigned)f2b(a[8+2*c]) | ((unsigned)f2b(a[9+2*c]) << 16);
    }
    *(uix4*)(&so[row][sl*16])     = o0;
    *(uix4*)(&so[row][sl*16 + 8]) = o1;
  }
  __syncthreads();

  // A for GEMM1: [emb | sum_o]  (K = 512)
  uix4 A1[16];
  {
    const u16* ep = emb16 + (size_t)s_wid[r0 + m] * 256 + q * 8;
    #pragma unroll
    for (int j = 0; j < 8; ++j) A1[j] = *(const uix4*)(ep + j * 32);
    #pragma unroll
    for (int j = 0; j < 8; ++j) A1[8 + j] = *(const uix4*)(&so[r0 + m][j*32 + q*8]);
  }
  __syncthreads();   // all waves captured so -> safe to overwrite with h1

  // GEMM1: h1 = relu(inp @ Ui^T + Uib) -> so region (wave-private rows)
  for (int t = 0; t < 16; ++t){
    f32x4 acc = {0.f, 0.f, 0.f, 0.f};
    const u16* bp = Ui16 + (size_t)(t*16 + m) * 512 + q * 8;
    #pragma unroll
    for (int j = 0; j < 16; ++j) acc = mfma16(A1[j], *(const uix4*)(bp + j*32), acc);
    const float bias = Uib[t*16 + m];
    #pragma unroll
    for (int i = 0; i < 4; ++i)
      so[r0 + q*4 + i][t*16 + m] = f2b(fmaxf(acc[i] + bias, 0.f));
  }
  __syncthreads();

  // GEMM2: h2 = relu([h1 | xtree] @ Uw^T + Ub); s = h2 . Uo + Uob
  uix4 A2[12];
  {
    #pragma unroll
    for (int j = 0; j < 8; ++j) A2[j] = *(const uix4*)(&so[r0 + m][j*32 + q*8]);
    const u16* xp = xt16 + (size_t)s_ctx[r0 + m] * 128 + q * 8;
    #pragma unroll
    for (int j = 0; j < 4; ++j) A2[8 + j] = *(const uix4*)(xp + j * 32);
  }
  float sp[4] = {0.f, 0.f, 0.f, 0.f};
  uix4 Bf[12];
  {
    const u16* bp = Uw16 + (size_t)m * 384 + q * 8;
    #pragma unroll
    for (int j = 0; j < 12; ++j) Bf[j] = *(const uix4*)(bp + j*32);
  }
  for (int t = 0; t < 16; ++t){
    uix4 Bn[12];
    if (t < 15){
      const u16* bp = Uw16 + (size_t)((t+1)*16 + m) * 384 + q * 8;
      #pragma unroll
      for (int j = 0; j < 12; ++j) Bn[j] = *(const uix4*)(bp + j*32);
    } else {
      #pragma unroll
      for (int j = 0; j < 12; ++j) Bn[j] = Bf[j];
    }
    f32x4 acc = {0.f, 0.f, 0.f, 0.f};
    #pragma unroll
    for (int j = 0; j < 12; ++j) acc = mfma16(A2[j], Bf[j], acc);
    const int c = t*16 + m;
    const float bias = Ub[c];
    const float uo   = Uo[c];
    #pragma unroll
    for (int i = 0; i < 4; ++i) sp[i] += fmaxf(acc[i] + bias, 0.f) * uo;
    #pragma unroll
    for (int j = 0; j < 12; ++j) Bf[j] = Bn[j];
  }
  #pragma unroll
  for (int msk = 1; msk < 16; msk <<= 1){
    #pragma unroll
    for (int i = 0; i < 4; ++i) sp[i] += __shfl_xor(sp[i], msk, 64);
  }
  if (m == 0){
    const float ub = Uob[0];
    #pragma unroll
    for (int i = 0; i < 4; ++i){
      const int r = r0 + q*4 + i;
      const float s   = sp[i] + ub;
      const float tgt = s_tgt[r];
      s_b0[r] = fmaxf(s, 0.f) - s * tgt + log1pf(__expf(-fabsf(s)));
      const float pb = (s >= 0.f) ? 1.f : 0.f;
      s_b1[r] = (pb == tgt) ? 1.f : 0.f;
    }
  }
  __syncthreads();
  if (tid < 64){
    float a = s_b0[tid], b = s_b1[tid];
    #pragma unroll
    for (int off = 32; off > 0; off >>= 1){
      a += __shfl_down(a, off, 64); b += __shfl_down(b, off, 64);
    }
    if (tid == 0){ atomicAdd(&accum[3], a); atomicAdd(&accum[4], b); }
  }
}

// ---- finalize --------------------------------------------------------------
__global__ void k_final(const float* __restrict__ acc, float* __restrict__ out){
  if (threadIdx.x == 0 && blockIdx.x == 0){
    out[0] = acc[0] / (float)B_;               // pred_loss
    out[1] = acc[3] / (float)B_;               // stop_loss
    out[2] = acc[1] / acc[2];                  // pred_acc
    out[3] = acc[4] / (float)(E_ + B_);        // stop_acc
  }
}

} // anonymous namespace

extern "C" void kernel_launch(void* const* d_in, const int* in_sizes, int n_in,
                              void* d_out, int out_size, void* d_ws, size_t ws_size,
                              hipStream_t stream)
{
  const float* emb   = (const float*)d_in[0];
  const float* Wz    = (const float*)d_in[1];
  const float* Wzb   = (const float*)d_in[2];
  const float* Wr    = (const float*)d_in[3];
  const float* Wrb   = (const float*)d_in[4];
  const float* Ur    = (const float*)d_in[5];
  const float* Wh    = (const float*)d_in[6];
  const float* Whb   = (const float*)d_in[7];
  const float* Ww    = (const float*)d_in[8];
  const float* Wb    = (const float*)d_in[9];
  const float* Wo    = (const float*)d_in[10];
  const float* Wob   = (const float*)d_in[11];
  const float* Uw    = (const float*)d_in[12];
  const float* Ub    = (const float*)d_in[13];
  const float* Ui    = (const float*)d_in[14];
  const float* Uib   = (const float*)d_in[15];
  const float* Uo    = (const float*)d_in[16];
  const float* Uob   = (const float*)d_in[17];
  const float* xtree = (const float*)d_in[18];
  const int* word_ids      = (const int*)d_in[19];
  const int* h_nei_idx     = (const int*)d_in[20];
  const int* o_nei_idx     = (const int*)d_in[21];
  const int* contexts      = (const int*)d_in[22];
  const int* pred_targets  = (const int*)d_in[23];
  const int* direction     = (const int*)d_in[24];
  const int* root_word_ids = (const int*)d_in[25];
  const int* root_o_idx    = (const int*)d_in[26];

  char*  wsb   = (char*)d_ws;
  float* accum = (float*)wsb;
  size_t off = 256;
  u16* hb16  = (u16*)(wsb + off); off += (size_t)(E_ + 1) * H_ * 2;  // 16.78 MB
  u16* emb16 = (u16*)(wsb + off); off += 204800u * 2;
  u16* xt16  = (u16*)(wsb + off); off += 32768u * 2;
  u16* Ww16  = (u16*)(wsb + off); off += 98304u * 2;
  u16* Wo16  = (u16*)(wsb + off); off += 204800u * 2;
  u16* Ui16  = (u16*)(wsb + off); off += 131072u * 2;
  u16* Uw16  = (u16*)(wsb + off); off += 98304u * 2;
  u16* Wz16  = (u16*)(wsb + off); off += 131072u * 2;
  u16* Wr16  = (u16*)(wsb + off); off += 65536u * 2;
  u16* Ur16  = (u16*)(wsb + off); off += 65536u * 2;
  u16* Wh16  = (u16*)(wsb + off); off += 131072u * 2;
  float* out = (float*)d_out;

  hipLaunchKernelGGL(k_cvt, dim3(4544), dim3(256), 0, stream,
                     emb, xtree, Ww, Wo, Ui, Uw, Wz, Wr, Ur, Wh,
                     emb16, xt16, Ww16, Wo16, Ui16, Uw16,
                     Wz16, Wr16, Ur16, Wh16);
  hipLaunchKernelGGL(k_init, dim3(1), dim3(256), 0, stream, accum, hb16);

  for (int t = 0; t < T_; ++t){
    hipLaunchKernelGGL(k_gru, dim3(N_ / 4), dim3(256), 0, stream,
                       emb16, Wz16, Wzb, Wr16, Wrb, Ur16, Wh16, Whb,
                       word_ids, h_nei_idx, hb16, t);
  }

  hipLaunchKernelGGL(k_pred, dim3((B_ + E_) / 64), dim3(256), 0, stream,
                     hb16, Ww16, Wb, Wo16, Wob, xt16,
                     contexts, pred_targets, direction, root_word_ids, accum);

  hipLaunchKernelGGL(k_stop, dim3((E_ + B_) / 64), dim3(256), 0, stream,
                     hb16, emb16, Ui16, Uib, Uw16, Ub, Uo, Uob, xt16,
                     word_ids, o_nei_idx, contexts, direction,
                     root_word_ids, root_o_idx, accum);

  hipLaunchKernelGGL(k_final, dim3(1), dim3(1), 0, stream, accum, out);
}

// Round 5
// 1247.282 us; speedup vs baseline: 4.9604x; 1.1554x over previous
//
#include <hip/hip_runtime.h>
#include <math.h>

// ---------------------------------------------------------------------------
// JTNN decoder forward on MI355X.  v5: occupancy push.
//  * k_gru: 1024 threads (16 waves), each wave = 16-col output slice.
//    grid 256 -> 16 waves/CU (4/SIMD).  __launch_bounds__(1024,4) caps
//    VGPR at 128 so they're actually resident.
//  * k_heads: k_pred+k_stop merged into one dispatch (grid 516+516) with an
//    explicit LDS union (~39KB -> 4 blocks/CU) to overlap both heads.
//  * MFMA layouts (validated R2-R4): A[m=lane&15][k=32*kb+8*q+j],
//    B[k][n=lane&15], D[row=4*q+i][col=lane&15].
// ---------------------------------------------------------------------------

namespace {

constexpr int T_  = 32;
constexpr int N_  = 1024;
constexpr int H_  = 256;
constexpr int NB_ = 15;
constexpr int E_  = T_ * N_;      // 32768
constexpr int B_  = 256;
constexpr int PREDB_ = (B_ + E_) / 64;   // 516
constexpr int STOPB_ = (E_ + B_) / 64;   // 516

typedef unsigned short u16;
typedef unsigned int  uix4  __attribute__((ext_vector_type(4)));
typedef __bf16        bf16x8 __attribute__((ext_vector_type(8)));
typedef float         f32x4  __attribute__((ext_vector_type(4)));

__device__ __forceinline__ float sig_(float x){ return 1.f / (1.f + __expf(-x)); }

__device__ __forceinline__ float b2f(u16 u){
  union { unsigned int i; float f; } v; v.i = ((unsigned int)u) << 16; return v.f;
}
__device__ __forceinline__ u16 f2b(float f){
  union { float f; unsigned int i; } v; v.f = f;
  const unsigned int r = v.i + 0x7fffu + ((v.i >> 16) & 1u);
  return (u16)(r >> 16);
}
__device__ __forceinline__ f32x4 mfma16(uix4 a, uix4 b, f32x4 c){
  return __builtin_amdgcn_mfma_f32_16x16x32_bf16(
      __builtin_bit_cast(bf16x8, a), __builtin_bit_cast(bf16x8, b), c, 0, 0, 0);
}

// ---- fp32 -> bf16 conversion (once per launch) ----------------------------
__global__ __launch_bounds__(256) void k_cvt(
    const float* __restrict__ emb, const float* __restrict__ xt,
    const float* __restrict__ Ww,  const float* __restrict__ Wo,
    const float* __restrict__ Ui,  const float* __restrict__ Uw,
    const float* __restrict__ Wz,  const float* __restrict__ Wr,
    const float* __restrict__ Ur,  const float* __restrict__ Wh,
    u16* __restrict__ o_emb, u16* __restrict__ o_xt, u16* __restrict__ o_Ww,
    u16* __restrict__ o_Wo,  u16* __restrict__ o_Ui, u16* __restrict__ o_Uw,
    u16* __restrict__ o_Wz,  u16* __restrict__ o_Wr, u16* __restrict__ o_Ur,
    u16* __restrict__ o_Wh)
{
  int i = blockIdx.x * 256 + threadIdx.x;
  if (i < 204800){ o_emb[i] = f2b(emb[i]); return; }  i -= 204800;
  if (i <  32768){ o_xt[i]  = f2b(xt[i]);  return; }  i -=  32768;
  if (i <  98304){ o_Ww[i]  = f2b(Ww[i]);  return; }  i -=  98304;
  if (i < 204800){ o_Wo[i]  = f2b(Wo[i]);  return; }  i -= 204800;
  if (i < 131072){ o_Ui[i]  = f2b(Ui[i]);  return; }  i -= 131072;
  if (i <  98304){ o_Uw[i]  = f2b(Uw[i]);  return; }  i -=  98304;
  if (i < 131072){ o_Wz[i]  = f2b(Wz[i]);  return; }  i -= 131072;
  if (i <  65536){ o_Wr[i]  = f2b(Wr[i]);  return; }  i -=  65536;
  if (i <  65536){ o_Ur[i]  = f2b(Ur[i]);  return; }  i -=  65536;
  if (i < 131072){ o_Wh[i]  = f2b(Wh[i]); }
}

// ---- init ------------------------------------------------------------------
__global__ __launch_bounds__(256) void k_init(float* __restrict__ acc,
                                              u16* __restrict__ hb16){
  const int tid = threadIdx.x;
  if (tid < 16) acc[tid] = 0.f;
  hb16[(size_t)E_ * H_ + tid] = 0;   // row E = zero pad slot
}

// ---- one GRU scan step: 1024 threads, 16 waves, wave = 16-col slice -------
// (row,nb) pairs packed 16/A-tile, pair = nb*4 + row -> D row 4q+i maps to
// (msg row=i, nb=4j+q); nb=15 pad = hbuf row E (zeros).
__global__ __launch_bounds__(1024, 4) void k_gru(
    const u16* __restrict__ emb16,
    const u16* __restrict__ Wz16, const float* __restrict__ Wzb,
    const u16* __restrict__ Wr16, const float* __restrict__ Wrb,
    const u16* __restrict__ Ur16,
    const u16* __restrict__ Wh16, const float* __restrict__ Whb,
    const int* __restrict__ word_ids, const int* __restrict__ h_nei,
    u16* __restrict__ hb16, int t)
{
  __shared__ __align__(16) u16 hn[64 * 264];   // 64 (row,nb) pairs, padded
  __shared__ __align__(16) u16 xs[4][264];     // embedding rows
  __shared__ __align__(16) u16 sh[4][264];     // sum_h (A-layout)
  __shared__ __align__(16) u16 gl[4][264];     // gated (A-layout)
  __shared__ int s_wid[4];
  __shared__ int s_hidx[64];                   // pair p = nb*4 + row

  const int tid = threadIdx.x;
  const int w = tid >> 6, ln = tid & 63, q = ln >> 4, m = ln & 15;
  const int col  = w * 16 + m;                 // this wave-lane's output col
  const int base = t * N_ + blockIdx.x * 4;    // first message row

  if (tid < 4) s_wid[tid] = word_ids[base + tid];
  if (tid < 64){
    const int row = tid & 3, nb = tid >> 2;
    s_hidx[tid] = (nb < NB_) ? h_nei[(base + row) * NB_ + nb] : E_;
  }
  __syncthreads();

  // stage 64 pair-rows (512B coalesced each) + 4 embedding rows
  #pragma unroll
  for (int it = 0; it < 2; ++it){
    const int task = it * 1024 + tid;
    const int row = task >> 5, ch = task & 31;
    *(uix4*)(&hn[row*264 + ch*8]) =
        *(const uix4*)(hb16 + (size_t)s_hidx[row]*256 + ch*8);
  }
  if (tid < 128){
    const int row = tid >> 5, ch = tid & 31;
    *(uix4*)(&xs[row][ch*8]) =
        *(const uix4*)(emb16 + (size_t)s_wid[row]*256 + ch*8);
  }
  __syncthreads();

  // A-frag of x (rows replicated m&3)
  uix4 Ax[8];
  #pragma unroll
  for (int kb = 0; kb < 8; ++kb) Ax[kb] = *(const uix4*)(&xs[m & 3][kb*32 + q*8]);

  // xr = x @ Wr^T + b_r  (C-init tile; D row 4q+i == message i)
  f32x4 xr = {0.f, 0.f, 0.f, 0.f};
  {
    const u16* bp = Wr16 + (size_t)col * 256 + q * 8;
    #pragma unroll
    for (int kb = 0; kb < 8; ++kb) xr = mfma16(Ax[kb], *(const uix4*)(bp + kb*32), xr);
    const float bias = Wrb[col];
    #pragma unroll
    for (int i = 0; i < 4; ++i) xr[i] += bias;
  }

  // persistent Ur B-frags for this wave's 16 cols (8 uix4 = 32 VGPR)
  uix4 Bur[8];
  {
    const u16* bp = Ur16 + (size_t)col * 256 + q * 8;
    #pragma unroll
    for (int kb = 0; kb < 8; ++kb) Bur[kb] = *(const uix4*)(bp + kb*32);
  }

  // r-gate GEMM over 4 pair-tiles; accumulate ga/su per (msg row=i, nb=4j+q)
  float ga[4] = {0.f,0.f,0.f,0.f}, su[4] = {0.f,0.f,0.f,0.f};
  #pragma unroll
  for (int j = 0; j < 4; ++j){
    uix4 Ah[8];
    #pragma unroll
    for (int kb = 0; kb < 8; ++kb)
      Ah[kb] = *(const uix4*)(&hn[(j*16 + m)*264 + kb*32 + q*8]);
    f32x4 a = xr;
    #pragma unroll
    for (int kb = 0; kb < 8; ++kb) a = mfma16(Ah[kb], Bur[kb], a);
    #pragma unroll
    for (int i = 0; i < 4; ++i){
      const float hv = b2f(hn[(j*16 + 4*q + i)*264 + col]);
      ga[i] += sig_(a[i]) * hv;
      su[i] += hv;
    }
  }

  // reduce over nb partition (quads): nb = 4j+q -> sum over q
  #pragma unroll
  for (int i = 0; i < 4; ++i){
    ga[i] += __shfl_xor(ga[i], 16, 64);
    ga[i] += __shfl_xor(ga[i], 32, 64);
    su[i] += __shfl_xor(su[i], 16, 64);
    su[i] += __shfl_xor(su[i], 32, 64);
  }
  if (q == 0){
    #pragma unroll
    for (int i = 0; i < 4; ++i){
      sh[i][col] = f2b(su[i]);
      gl[i][col] = f2b(ga[i]);
    }
  }
  __syncthreads();

  // z / h~ GEMMs (K=512), combine, store (q==0 lanes own real rows 0..3)
  f32x4 az = {0.f,0.f,0.f,0.f}, ah = {0.f,0.f,0.f,0.f};
  {
    uix4 As[8];
    #pragma unroll
    for (int kb = 0; kb < 8; ++kb) As[kb] = *(const uix4*)(&sh[m & 3][kb*32 + q*8]);
    const u16* bz = Wz16 + (size_t)col * 512 + q * 8;
    #pragma unroll
    for (int kb = 0; kb < 8; ++kb) az = mfma16(Ax[kb], *(const uix4*)(bz + kb*32), az);
    #pragma unroll
    for (int kb = 0; kb < 8; ++kb) az = mfma16(As[kb], *(const uix4*)(bz + 256 + kb*32), az);
  }
  {
    uix4 Ag[8];
    #pragma unroll
    for (int kb = 0; kb < 8; ++kb) Ag[kb] = *(const uix4*)(&gl[m & 3][kb*32 + q*8]);
    const u16* bh = Wh16 + (size_t)col * 512 + q * 8;
    #pragma unroll
    for (int kb = 0; kb < 8; ++kb) ah = mfma16(Ax[kb], *(const uix4*)(bh + kb*32), ah);
    #pragma unroll
    for (int kb = 0; kb < 8; ++kb) ah = mfma16(Ag[kb], *(const uix4*)(bh + 256 + kb*32), ah);
  }
  if (q == 0){
    const float zb = Wzb[col], hb = Whb[col];
    #pragma unroll
    for (int i = 0; i < 4; ++i){
      const float z  = sig_(az[i] + zb);
      const float ht = tanhf(ah[i] + hb);
      const float nh = (1.f - z) * su[i] + z * ht;
      hb16[(size_t)(base + i) * 256 + col] = f2b(nh);
    }
  }
}

// ---- merged heads ----------------------------------------------------------
struct PredSm {
  u16   hd[4][16][264];
  int   tgt[64];
  float mask[64];
  float nll[64], hit[64], msk[64];
};
struct StopSm {
  u16   so[64][264];
  int   oidx[64][NB_];
  int   wid[64], ctx[64];
  float tgt[64];
  float b0[64], b1[64];
};
constexpr size_t SMU_ = sizeof(StopSm) > sizeof(PredSm) ? sizeof(StopSm)
                                                        : sizeof(PredSm);

__device__ void pred_body(int bid, char* smraw,
    const u16* __restrict__ hb16, const u16* __restrict__ Ww16,
    const float* __restrict__ Wb, const u16* __restrict__ Wo16,
    const float* __restrict__ Wob, const u16* __restrict__ xt16,
    const int* __restrict__ contexts, const int* __restrict__ pred_targets,
    const int* __restrict__ direction, const int* __restrict__ root_word_ids,
    float* __restrict__ accum)
{
  PredSm& sm = *(PredSm*)smraw;
  const int tid = threadIdx.x;
  const int p0  = bid * 64;
  const int w = tid >> 6, ln = tid & 63, q = ln >> 4, m = ln & 15;
  const int r0 = w * 16;

  if (tid < 64){
    const int p = p0 + tid;
    int tg; float mk;
    if (p < B_){ tg = root_word_ids[p]; mk = 1.f; }
    else { tg = pred_targets[p - B_]; mk = (float)direction[p - B_]; }
    sm.tgt[tid] = tg; sm.mask[tid] = mk;
  }
  const int p    = p0 + r0 + m;
  const int hrow = (p < B_) ? E_ : (p - B_);
  const int ctx  = (p < B_) ? p  : contexts[p - B_];
  __syncthreads();

  // GEMM1: hid = relu([h | xtree] @ Ww^T + Wb)   (K = 384)
  uix4 A1[12];
  {
    const u16* hp = hb16 + (size_t)hrow * 256 + q * 8;
    #pragma unroll
    for (int j = 0; j < 8; ++j) A1[j] = *(const uix4*)(hp + j * 32);
    const u16* xp = xt16 + (size_t)ctx * 128 + q * 8;
    #pragma unroll
    for (int j = 0; j < 4; ++j) A1[8 + j] = *(const uix4*)(xp + j * 32);
  }
  for (int t = 0; t < 16; ++t){
    f32x4 acc = {0.f, 0.f, 0.f, 0.f};
    const u16* bp = Ww16 + (size_t)(t*16 + m) * 384 + q * 8;
    #pragma unroll
    for (int j = 0; j < 12; ++j) acc = mfma16(A1[j], *(const uix4*)(bp + j*32), acc);
    const float bias = Wb[t*16 + m];
    #pragma unroll
    for (int i = 0; i < 4; ++i)
      sm.hd[w][q*4 + i][t*16 + m] = f2b(fmaxf(acc[i] + bias, 0.f));
  }
  __syncthreads();

  // GEMM2: scores = hid @ Wo^T + Wob, online softmax, B-prefetch
  uix4 A2[8];
  #pragma unroll
  for (int j = 0; j < 8; ++j) A2[j] = *(const uix4*)(&sm.hd[w][m][j*32 + q*8]);

  int tgtc[4];
  #pragma unroll
  for (int i = 0; i < 4; ++i) tgtc[i] = sm.tgt[r0 + q*4 + i];
  float mrun[4], lrun[4], amax[4], tval[4]; int aidx[4];
  #pragma unroll
  for (int i = 0; i < 4; ++i){
    mrun[i] = -1e30f; lrun[i] = 0.f; amax[i] = -1e30f; tval[i] = -1e30f; aidx[i] = 0;
  }

  uix4 Bf[8];
  {
    const u16* bp = Wo16 + (size_t)m * 256 + q * 8;
    #pragma unroll
    for (int j = 0; j < 8; ++j) Bf[j] = *(const uix4*)(bp + j*32);
  }
  for (int t = 0; t < 50; ++t){
    uix4 Bn[8];
    if (t < 49){
      const u16* bp = Wo16 + (size_t)((t+1)*16 + m) * 256 + q * 8;
      #pragma unroll
      for (int j = 0; j < 8; ++j) Bn[j] = *(const uix4*)(bp + j*32);
    } else {
      #pragma unroll
      for (int j = 0; j < 8; ++j) Bn[j] = Bf[j];
    }
    f32x4 acc = {0.f, 0.f, 0.f, 0.f};
    #pragma unroll
    for (int j = 0; j < 8; ++j) acc = mfma16(A2[j], Bf[j], acc);
    const int c = t*16 + m;
    const float bias = Wob[c];
    #pragma unroll
    for (int i = 0; i < 4; ++i){
      const float v = acc[i] + bias;
      if (c == tgtc[i]) tval[i] = v;
      if (v > amax[i]){ amax[i] = v; aidx[i] = c; }
      const float nm = fmaxf(mrun[i], v);
      lrun[i] = lrun[i] * __expf(mrun[i] - nm) + __expf(v - nm);
      mrun[i] = nm;
    }
    #pragma unroll
    for (int j = 0; j < 8; ++j) Bf[j] = Bn[j];
  }
  #pragma unroll
  for (int msk = 1; msk < 16; msk <<= 1){
    #pragma unroll
    for (int i = 0; i < 4; ++i){
      const float om = __shfl_xor(mrun[i], msk, 64);
      const float ol = __shfl_xor(lrun[i], msk, 64);
      const float nm = fmaxf(mrun[i], om);
      lrun[i] = lrun[i] * __expf(mrun[i] - nm) + ol * __expf(om - nm);
      mrun[i] = nm;
      const float oa = __shfl_xor(amax[i], msk, 64);
      const int   oi = __shfl_xor(aidx[i], msk, 64);
      if (oa > amax[i] || (oa == amax[i] && oi < aidx[i])){ amax[i] = oa; aidx[i] = oi; }
      tval[i] = fmaxf(tval[i], __shfl_xor(tval[i], msk, 64));
    }
  }
  if (m == 0){
    #pragma unroll
    for (int i = 0; i < 4; ++i){
      const int r = r0 + q*4 + i;
      const float mk  = sm.mask[r];
      const float nll = mrun[i] + __logf(lrun[i]) - tval[i];
      sm.nll[r] = nll * mk;
      sm.hit[r] = (aidx[i] == tgtc[i]) ? mk : 0.f;
      sm.msk[r] = mk;
    }
  }
  __syncthreads();
  if (tid < 64){
    float a = sm.nll[tid], b = sm.hit[tid], c2 = sm.msk[tid];
    #pragma unroll
    for (int off = 32; off > 0; off >>= 1){
      a += __shfl_down(a, off, 64); b += __shfl_down(b, off, 64); c2 += __shfl_down(c2, off, 64);
    }
    if (tid == 0){
      atomicAdd(&accum[0], a); atomicAdd(&accum[1], b); atomicAdd(&accum[2], c2);
    }
  }
}

__device__ void stop_body(int bid, char* smraw,
    const u16* __restrict__ hb16, const u16* __restrict__ emb16,
    const u16* __restrict__ Ui16, const float* __restrict__ Uib,
    const u16* __restrict__ Uw16, const float* __restrict__ Ub,
    const float* __restrict__ Uo, const float* __restrict__ Uob,
    const u16* __restrict__ xt16,
    const int* __restrict__ word_ids, const int* __restrict__ o_nei,
    const int* __restrict__ contexts, const int* __restrict__ direction,
    const int* __restrict__ root_word_ids, const int* __restrict__ root_o_idx,
    float* __restrict__ accum)
{
  StopSm& sm = *(StopSm*)smraw;
  const int tid = threadIdx.x;
  const int p0  = bid * 64;
  const int w = tid >> 6, ln = tid & 63, q = ln >> 4, m = ln & 15;
  const int r0 = w * 16;

  if (tid < 64){
    const int s = p0 + tid;
    if (s < E_){ sm.wid[tid] = word_ids[s]; sm.ctx[tid] = contexts[s];
                 sm.tgt[tid] = (float)direction[s]; }
    else { const int b = s - E_; sm.wid[tid] = root_word_ids[b]; sm.ctx[tid] = b;
           sm.tgt[tid] = 0.f; }
  }
  for (int k = tid; k < 64 * NB_; k += 256){
    const int r = k / NB_, nb = k % NB_;
    const int s = p0 + r;
    sm.oidx[r][nb] = (s < E_) ? o_nei[(size_t)s * NB_ + nb]
                              : root_o_idx[(size_t)(s - E_) * NB_ + nb];
  }
  __syncthreads();

  // stage sum_o: task-parallel (row, 16-col slice), coalesced uix4 gathers
  for (int it = 0; it < 4; ++it){
    const int task = it * 256 + tid;
    const int row = task >> 4, sl = task & 15;
    float a[16];
    #pragma unroll
    for (int c = 0; c < 16; ++c) a[c] = 0.f;
    #pragma unroll
    for (int nb = 0; nb < NB_; ++nb){
      const u16* p = hb16 + (size_t)sm.oidx[row][nb] * 256 + sl * 16;
      const uix4 v0 = *(const uix4*)(p);
      const uix4 v1 = *(const uix4*)(p + 8);
      #pragma unroll
      for (int c = 0; c < 4; ++c){
        a[2*c]     += b2f((u16)(v0[c] & 0xffffu));
        a[2*c + 1] += b2f((u16)(v0[c] >> 16));
        a[8 + 2*c] += b2f((u16)(v1[c] & 0xffffu));
        a[9 + 2*c] += b2f((u16)(v1[c] >> 16));
      }
    }
    uix4 o0, o1;
    #pragma unroll
    for (int c = 0; c < 4; ++c){
      o0[c] = (unsigned)f2b(a[2*c])   | ((unsigned)f2b(a[2*c+1]) << 16);
      o1[c] = (unsigned)f2b(a[8+2*c]) | ((unsigned)f2b(a[9+2*c]) << 16);
    }
    *(uix4*)(&sm.so[row][sl*16])     = o0;
    *(uix4*)(&sm.so[row][sl*16 + 8]) = o1;
  }
  __syncthreads();

  // A for GEMM1: [emb | sum_o]  (K = 512)
  uix4 A1[16];
  {
    const u16* ep = emb16 + (size_t)sm.wid[r0 + m] * 256 + q * 8;
    #pragma unroll
    for (int j = 0; j < 8; ++j) A1[j] = *(const uix4*)(ep + j * 32);
    #pragma unroll
    for (int j = 0; j < 8; ++j) A1[8 + j] = *(const uix4*)(&sm.so[r0 + m][j*32 + q*8]);
  }
  __syncthreads();   // all waves captured so -> safe to overwrite with h1

  // GEMM1: h1 = relu(inp @ Ui^T + Uib) -> so region (wave-private rows)
  for (int t = 0; t < 16; ++t){
    f32x4 acc = {0.f, 0.f, 0.f, 0.f};
    const u16* bp = Ui16 + (size_t)(t*16 + m) * 512 + q * 8;
    #pragma unroll
    for (int j = 0; j < 16; ++j) acc = mfma16(A1[j], *(const uix4*)(bp + j*32), acc);
    const float bias = Uib[t*16 + m];
    #pragma unroll
    for (int i = 0; i < 4; ++i)
      sm.so[r0 + q*4 + i][t*16 + m] = f2b(fmaxf(acc[i] + bias, 0.f));
  }
  __syncthreads();

  // GEMM2: h2 = relu([h1 | xtree] @ Uw^T + Ub); s = h2 . Uo + Uob
  uix4 A2[12];
  {
    #pragma unroll
    for (int j = 0; j < 8; ++j) A2[j] = *(const uix4*)(&sm.so[r0 + m][j*32 + q*8]);
    const u16* xp = xt16 + (size_t)sm.ctx[r0 + m] * 128 + q * 8;
    #pragma unroll
    for (int j = 0; j < 4; ++j) A2[8 + j] = *(const uix4*)(xp + j * 32);
  }
  float sp[4] = {0.f, 0.f, 0.f, 0.f};
  uix4 Bf[12];
  {
    const u16* bp = Uw16 + (size_t)m * 384 + q * 8;
    #pragma unroll
    for (int j = 0; j < 12; ++j) Bf[j] = *(const uix4*)(bp + j*32);
  }
  for (int t = 0; t < 16; ++t){
    uix4 Bn[12];
    if (t < 15){
      const u16* bp = Uw16 + (size_t)((t+1)*16 + m) * 384 + q * 8;
      #pragma unroll
      for (int j = 0; j < 12; ++j) Bn[j] = *(const uix4*)(bp + j*32);
    } else {
      #pragma unroll
      for (int j = 0; j < 12; ++j) Bn[j] = Bf[j];
    }
    f32x4 acc = {0.f, 0.f, 0.f, 0.f};
    #pragma unroll
    for (int j = 0; j < 12; ++j) acc = mfma16(A2[j], Bf[j], acc);
    const int c = t*16 + m;
    const float bias = Ub[c];
    const float uo   = Uo[c];
    #pragma unroll
    for (int i = 0; i < 4; ++i) sp[i] += fmaxf(acc[i] + bias, 0.f) * uo;
    #pragma unroll
    for (int j = 0; j < 12; ++j) Bf[j] = Bn[j];
  }
  #pragma unroll
  for (int msk = 1; msk < 16; msk <<= 1){
    #pragma unroll
    for (int i = 0; i < 4; ++i) sp[i] += __shfl_xor(sp[i], msk, 64);
  }
  if (m == 0){
    const float ub = Uob[0];
    #pragma unroll
    for (int i = 0; i < 4; ++i){
      const int r = r0 + q*4 + i;
      const float s   = sp[i] + ub;
      const float tgt = sm.tgt[r];
      sm.b0[r] = fmaxf(s, 0.f) - s * tgt + log1pf(__expf(-fabsf(s)));
      const float pb = (s >= 0.f) ? 1.f : 0.f;
      sm.b1[r] = (pb == tgt) ? 1.f : 0.f;
    }
  }
  __syncthreads();
  if (tid < 64){
    float a = sm.b0[tid], b = sm.b1[tid];
    #pragma unroll
    for (int off = 32; off > 0; off >>= 1){
      a += __shfl_down(a, off, 64); b += __shfl_down(b, off, 64);
    }
    if (tid == 0){ atomicAdd(&accum[3], a); atomicAdd(&accum[4], b); }
  }
}

__global__ __launch_bounds__(256) void k_heads(
    const u16* __restrict__ hb16, const u16* __restrict__ emb16,
    const u16* __restrict__ Ww16, const float* __restrict__ Wb,
    const u16* __restrict__ Wo16, const float* __restrict__ Wob,
    const u16* __restrict__ Ui16, const float* __restrict__ Uib,
    const u16* __restrict__ Uw16, const float* __restrict__ Ub,
    const float* __restrict__ Uo, const float* __restrict__ Uob,
    const u16* __restrict__ xt16,
    const int* __restrict__ word_ids, const int* __restrict__ o_nei,
    const int* __restrict__ contexts, const int* __restrict__ pred_targets,
    const int* __restrict__ direction, const int* __restrict__ root_word_ids,
    const int* __restrict__ root_o_idx, float* __restrict__ accum)
{
  __shared__ __align__(16) char smraw[SMU_];
  const int b = blockIdx.x;
  if (b < PREDB_){
    pred_body(b, smraw, hb16, Ww16, Wb, Wo16, Wob, xt16,
              contexts, pred_targets, direction, root_word_ids, accum);
  } else {
    stop_body(b - PREDB_, smraw, hb16, emb16, Ui16, Uib, Uw16, Ub, Uo, Uob,
              xt16, word_ids, o_nei, contexts, direction,
              root_word_ids, root_o_idx, accum);
  }
}

// ---- finalize --------------------------------------------------------------
__global__ void k_final(const float* __restrict__ acc, float* __restrict__ out){
  if (threadIdx.x == 0 && blockIdx.x == 0){
    out[0] = acc[0] / (float)B_;               // pred_loss
    out[1] = acc[3] / (float)B_;               // stop_loss
    out[2] = acc[1] / acc[2];                  // pred_acc
    out[3] = acc[4] / (float)(E_ + B_);        // stop_acc
  }
}

} // anonymous namespace

extern "C" void kernel_launch(void* const* d_in, const int* in_sizes, int n_in,
                              void* d_out, int out_size, void* d_ws, size_t ws_size,
                              hipStream_t stream)
{
  const float* emb   = (const float*)d_in[0];
  const float* Wz    = (const float*)d_in[1];
  const float* Wzb   = (const float*)d_in[2];
  const float* Wr    = (const float*)d_in[3];
  const float* Wrb   = (const float*)d_in[4];
  const float* Ur    = (const float*)d_in[5];
  const float* Wh    = (const float*)d_in[6];
  const float* Whb   = (const float*)d_in[7];
  const float* Ww    = (const float*)d_in[8];
  const float* Wb    = (const float*)d_in[9];
  const float* Wo    = (const float*)d_in[10];
  const float* Wob   = (const float*)d_in[11];
  const float* Uw    = (const float*)d_in[12];
  const float* Ub    = (const float*)d_in[13];
  const float* Ui    = (const float*)d_in[14];
  const float* Uib   = (const float*)d_in[15];
  const float* Uo    = (const float*)d_in[16];
  const float* Uob   = (const float*)d_in[17];
  const float* xtree = (const float*)d_in[18];
  const int* word_ids      = (const int*)d_in[19];
  const int* h_nei_idx     = (const int*)d_in[20];
  const int* o_nei_idx     = (const int*)d_in[21];
  const int* contexts      = (const int*)d_in[22];
  const int* pred_targets  = (const int*)d_in[23];
  const int* direction     = (const int*)d_in[24];
  const int* root_word_ids = (const int*)d_in[25];
  const int* root_o_idx    = (const int*)d_in[26];

  char*  wsb   = (char*)d_ws;
  float* accum = (float*)wsb;
  size_t off = 256;
  u16* hb16  = (u16*)(wsb + off); off += (size_t)(E_ + 1) * H_ * 2;  // 16.78 MB
  u16* emb16 = (u16*)(wsb + off); off += 204800u * 2;
  u16* xt16  = (u16*)(wsb + off); off += 32768u * 2;
  u16* Ww16  = (u16*)(wsb + off); off += 98304u * 2;
  u16* Wo16  = (u16*)(wsb + off); off += 204800u * 2;
  u16* Ui16  = (u16*)(wsb + off); off += 131072u * 2;
  u16* Uw16  = (u16*)(wsb + off); off += 98304u * 2;
  u16* Wz16  = (u16*)(wsb + off); off += 131072u * 2;
  u16* Wr16  = (u16*)(wsb + off); off += 65536u * 2;
  u16* Ur16  = (u16*)(wsb + off); off += 65536u * 2;
  u16* Wh16  = (u16*)(wsb + off); off += 131072u * 2;
  float* out = (float*)d_out;

  hipLaunchKernelGGL(k_cvt, dim3(4544), dim3(256), 0, stream,
                     emb, xtree, Ww, Wo, Ui, Uw, Wz, Wr, Ur, Wh,
                     emb16, xt16, Ww16, Wo16, Ui16, Uw16,
                     Wz16, Wr16, Ur16, Wh16);
  hipLaunchKernelGGL(k_init, dim3(1), dim3(256), 0, stream, accum, hb16);

  for (int t = 0; t < T_; ++t){
    hipLaunchKernelGGL(k_gru, dim3(N_ / 4), dim3(1024), 0, stream,
                       emb16, Wz16, Wzb, Wr16, Wrb, Ur16, Wh16, Whb,
                       word_ids, h_nei_idx, hb16, t);
  }

  hipLaunchKernelGGL(k_heads, dim3(PREDB_ + STOPB_), dim3(256), 0, stream,
                     hb16, emb16, Ww16, Wb, Wo16, Wob, Ui16, Uib, Uw16, Ub,
                     Uo, Uob, xt16, word_ids, o_nei_idx, contexts,
                     pred_targets, direction, root_word_ids, root_o_idx,
                     accum);

  hipLaunchKernelGGL(k_final, dim3(1), dim3(1), 0, stream, accum, out);
}